// Round 5
// baseline (373.034 us; speedup 1.0000x reference)
//
#include <hip/hip_runtime.h>
#include <hip/hip_bf16.h>

#define D 256
#define G 512
#define PER 128
#define NROW (G*PER)   // 65536
#define LSEQ 1534
#define LP 1536
#define HID 512

typedef __hip_bfloat16 bf16;
typedef __attribute__((ext_vector_type(8))) short bf16x8;
typedef __attribute__((ext_vector_type(4))) float f32x4;

// MFMA B layout (conflict-free): within each 64KB chunk, fragment block
// (nt,kt) occupies 1KB; 16B unit index within block = lane = quad*16 + ln.
// Element (k,n): nt=(n>>4)&7, kt=k>>5, quad=(k>>3)&3, ln=n&15, e=k&7.

// ---------------------------------------------------------------------------
// K-zeroH: zero HAts (needed for uint atomicMax accumulation)
// ---------------------------------------------------------------------------
__global__ __launch_bounds__(256) void k_zeroH(float4* __restrict__ p) {
  p[blockIdx.x * 256 + threadIdx.x] = make_float4(0.f, 0.f, 0.f, 0.f);
}

// ---------------------------------------------------------------------------
// K-waprep: Wa (256x256 fp32, [k][n]) -> MFMA-tiled bf16 hi/lo buffers.
// ---------------------------------------------------------------------------
__global__ void k_waprep(const float* __restrict__ Wa,
                         bf16* __restrict__ WAhi, bf16* __restrict__ WAlo) {
  int id = blockIdx.x * 256 + threadIdx.x;   // id = k*256 + n
  int k = id >> 8, n = id & 255;
  float v = Wa[(size_t)k * D + n];
  bf16 h = __float2bfloat16(v);
  float hf = __bfloat162float(h);
  bf16 l = __float2bfloat16(v - hf);
  int dst = (n >> 7) * 32768
          + (((((n >> 4) & 7) * 8 + (k >> 5)) * 64 + ((k >> 3) & 3) * 16 + (n & 15)) * 8)
          + (k & 7);
  WAhi[dst] = h;
  WAlo[dst] = l;
}

// ---------------------------------------------------------------------------
// K1: hats = relu(NEs @ Wa + ba) via split-bf16 MFMA (AhiBhi+AloBhi+AhiBlo).
// ---------------------------------------------------------------------------
__global__ __launch_bounds__(256) void k_hats_mfma(
    const float* __restrict__ NEs, const bf16* __restrict__ WAhi,
    const bf16* __restrict__ WAlo, const float* __restrict__ ba,
    bf16* __restrict__ hats, float* __restrict__ HAts) {
  __shared__ __align__(16) unsigned short bs[32768];  // 64 KB (reused as bounce)
  __shared__ float wsmax[4][128];

  const int tid = threadIdx.x;
  const int wave = tid >> 6, lane = tid & 63;
  const int ln = lane & 15, quad = lane >> 4;
  const int row0 = blockIdx.x * 64;
  const int g = row0 >> 7;

  bf16x8 afH[8], afL[8];
  {
    const float4* ap = (const float4*)(NEs + (size_t)(row0 + wave*16 + ln) * D);
    #pragma unroll
    for (int kt = 0; kt < 8; ++kt) {
      float4 x0 = ap[kt*8 + quad*2];
      float4 x1 = ap[kt*8 + quad*2 + 1];
      float xv[8] = {x0.x, x0.y, x0.z, x0.w, x1.x, x1.y, x1.z, x1.w};
      bf16x8 hv, lv;
      #pragma unroll
      for (int e = 0; e < 8; ++e) {
        bf16 h = __float2bfloat16(xv[e]);
        bf16 l = __float2bfloat16(xv[e] - __bfloat162float(h));
        hv[e] = *(short*)&h;
        lv[e] = *(short*)&l;
      }
      afH[kt] = hv;
      afL[kt] = lv;
    }
  }

  float* bsf = (float*)bs;   // bounce view: [64][140] floats (35 KB)

  for (int chunk = 0; chunk < 2; ++chunk) {
    f32x4 acc[8];
    #pragma unroll
    for (int nt = 0; nt < 8; ++nt) acc[nt] = (f32x4){0.f, 0.f, 0.f, 0.f};

    __syncthreads();
    {
      const uint4* src = (const uint4*)(WAhi + (size_t)chunk * 32768);
      uint4* dst = (uint4*)bs;
      #pragma unroll
      for (int r = 0; r < 16; ++r) dst[r*256 + tid] = src[r*256 + tid];
    }
    __syncthreads();
    #pragma unroll
    for (int nt = 0; nt < 8; ++nt)
      #pragma unroll
      for (int kt = 0; kt < 8; ++kt) {
        const bf16x8 bfr = *(const bf16x8*)&bs[((nt*8 + kt)*64 + lane)*8];
        acc[nt] = __builtin_amdgcn_mfma_f32_16x16x32_bf16(afH[kt], bfr, acc[nt], 0, 0, 0);
        acc[nt] = __builtin_amdgcn_mfma_f32_16x16x32_bf16(afL[kt], bfr, acc[nt], 0, 0, 0);
      }

    __syncthreads();
    {
      const uint4* src = (const uint4*)(WAlo + (size_t)chunk * 32768);
      uint4* dst = (uint4*)bs;
      #pragma unroll
      for (int r = 0; r < 16; ++r) dst[r*256 + tid] = src[r*256 + tid];
    }
    __syncthreads();
    #pragma unroll
    for (int nt = 0; nt < 8; ++nt)
      #pragma unroll
      for (int kt = 0; kt < 8; ++kt) {
        const bf16x8 bfr = *(const bf16x8*)&bs[((nt*8 + kt)*64 + lane)*8];
        acc[nt] = __builtin_amdgcn_mfma_f32_16x16x32_bf16(afH[kt], bfr, acc[nt], 0, 0, 0);
      }

    __syncthreads();
    #pragma unroll
    for (int nt = 0; nt < 8; ++nt) {
      const float bv = ba[chunk*128 + nt*16 + ln];
      float m = 0.f;
      #pragma unroll
      for (int reg = 0; reg < 4; ++reg) {
        float h = acc[nt][reg] + bv;
        h = h > 0.f ? h : 0.f;
        bsf[(wave*16 + quad*4 + reg)*140 + nt*16 + ln] = h;
        m = fmaxf(m, h);
      }
      m = fmaxf(m, __shfl_xor(m, 16, 64));
      m = fmaxf(m, __shfl_xor(m, 32, 64));
      if (quad == 0) wsmax[wave][nt*16 + ln] = m;
    }
    __syncthreads();
    {
      const int row = tid >> 2, q4 = tid & 3;
      const float* rp = &bsf[row*140 + q4*32];
      bf16* gp = hats + (size_t)(row0 + row) * D + chunk*128 + q4*32;
      #pragma unroll
      for (int s = 0; s < 4; ++s) {
        float4 v0 = *(const float4*)&rp[s*8];
        float4 v1 = *(const float4*)&rp[s*8 + 4];
        float vv[8] = {v0.x, v0.y, v0.z, v0.w, v1.x, v1.y, v1.z, v1.w};
        bf16x8 pk;
        #pragma unroll
        for (int e = 0; e < 8; ++e) {
          bf16 b = __float2bfloat16(vv[e]);
          pk[e] = *(short*)&b;
        }
        *(bf16x8*)(gp + s*8) = pk;
      }
    }
    if (tid < 128) {
      float m = fmaxf(fmaxf(wsmax[0][tid], wsmax[1][tid]),
                      fmaxf(wsmax[2][tid], wsmax[3][tid]));
      atomicMax((unsigned int*)&HAts[(size_t)g*D + chunk*128 + tid],
                __float_as_uint(m));
    }
  }
}

// ---------------------------------------------------------------------------
// K-wconv: Wp1 rows 768..1023 (fp32) -> MFMA-tiled bf16 layout WBt.
// ---------------------------------------------------------------------------
__global__ void k_wconv(const float* __restrict__ Wp1, bf16* __restrict__ WBt) {
  int id = blockIdx.x * 256 + threadIdx.x;   // id = k*512 + n
  int k = id >> 9, n = id & 511;
  float v = Wp1[(size_t)(768 + k) * HID + n];
  int dst = (n >> 7) * 32768
          + (((((n >> 4) & 7) * 8 + (k >> 5)) * 64 + ((k >> 3) & 3) * 16 + (n & 15)) * 8)
          + (k & 7);
  WBt[dst] = __float2bfloat16(v);
}

// ---------------------------------------------------------------------------
// K-wp1prep: Wp1 rows 0..767 -> MFMA-tiled bf16 hi/lo. Tiles of
// (k-chunk 256) x (n-chunk 128), tile index = nc*3 + kc, 32768 elems each.
// ---------------------------------------------------------------------------
__global__ void k_wp1prep(const float* __restrict__ Wp1,
                          bf16* __restrict__ Bhi, bf16* __restrict__ Blo) {
  int id = blockIdx.x * 256 + threadIdx.x;   // id = k*512 + n, k<768
  int k = id >> 9, n = id & 511;
  float v = Wp1[(size_t)k * HID + n];
  bf16 h = __float2bfloat16(v);
  bf16 l = __float2bfloat16(v - __bfloat162float(h));
  int kc = k >> 8, kr = k & 255;
  int nc = n >> 7, nr = n & 127;
  int dst = (nc*3 + kc) * 32768
          + ((((nr >> 4) * 8 + (kr >> 5)) * 64 + ((kr >> 3) & 3) * 16 + (nr & 15)) * 8)
          + (kr & 7);
  Bhi[dst] = h;
  Blo[dst] = l;
}

// ---------------------------------------------------------------------------
// K-sprep: S = [query | hs | HAts] (512 x 768) -> row-major bf16 hi/lo
// ---------------------------------------------------------------------------
__global__ void k_sprep(const float* __restrict__ query,
                        const float* __restrict__ HAts,
                        const float* __restrict__ xfin,
                        bf16* __restrict__ Shi, bf16* __restrict__ Slo) {
  int m = blockIdx.x * 256 + threadIdx.x;   // 0..767
  int g = blockIdx.y;
  float v;
  if (m < 256)      v = query[(size_t)g*D + m];
  else if (m < 512) v = xfin[(size_t)(m - 256)*LP + 3*g];
  else              v = HAts[(size_t)g*D + (m - 512)];
  bf16 h = __float2bfloat16(v);
  bf16 l = __float2bfloat16(v - __bfloat162float(h));
  Shi[(size_t)g*768 + m] = h;
  Slo[(size_t)g*768 + m] = l;
}

// ---------------------------------------------------------------------------
// K4: Gterm = S @ Wp1[0:768] + bp1 via split-bf16 MFMA.
// ---------------------------------------------------------------------------
__global__ __launch_bounds__(256) void k_gterm_mfma(
    const bf16* __restrict__ Shi, const bf16* __restrict__ Slo,
    const bf16* __restrict__ WB1hi, const bf16* __restrict__ WB1lo,
    const float* __restrict__ bp1, float* __restrict__ Gterm) {
  __shared__ __align__(16) unsigned short bs[32768];  // 64 KB

  const int tid = threadIdx.x;
  const int wave = tid >> 6, lane = tid & 63;
  const int ln = lane & 15, quad = lane >> 4;
  const int nc = blockIdx.x;
  const int row0 = blockIdx.y * 64;

  f32x4 acc[8];
  #pragma unroll
  for (int nt = 0; nt < 8; ++nt) acc[nt] = (f32x4){0.f, 0.f, 0.f, 0.f};

  const uint4* ahp = (const uint4*)(Shi + (size_t)(row0 + wave*16 + ln) * 768);
  const uint4* alp = (const uint4*)(Slo + (size_t)(row0 + wave*16 + ln) * 768);

  for (int kc = 0; kc < 3; ++kc) {
    bf16x8 afH[8], afL[8];
    #pragma unroll
    for (int kt = 0; kt < 8; ++kt) {
      uint4 th = ahp[kc*32 + kt*4 + quad];
      uint4 tl = alp[kc*32 + kt*4 + quad];
      afH[kt] = *(const bf16x8*)&th;
      afL[kt] = *(const bf16x8*)&tl;
    }

    __syncthreads();
    {
      const uint4* src = (const uint4*)(WB1hi + (size_t)(nc*3 + kc) * 32768);
      uint4* dst = (uint4*)bs;
      #pragma unroll
      for (int r = 0; r < 16; ++r) dst[r*256 + tid] = src[r*256 + tid];
    }
    __syncthreads();
    #pragma unroll
    for (int nt = 0; nt < 8; ++nt)
      #pragma unroll
      for (int kt = 0; kt < 8; ++kt) {
        const bf16x8 bfr = *(const bf16x8*)&bs[((nt*8 + kt)*64 + lane)*8];
        acc[nt] = __builtin_amdgcn_mfma_f32_16x16x32_bf16(afH[kt], bfr, acc[nt], 0, 0, 0);
        acc[nt] = __builtin_amdgcn_mfma_f32_16x16x32_bf16(afL[kt], bfr, acc[nt], 0, 0, 0);
      }

    __syncthreads();
    {
      const uint4* src = (const uint4*)(WB1lo + (size_t)(nc*3 + kc) * 32768);
      uint4* dst = (uint4*)bs;
      #pragma unroll
      for (int r = 0; r < 16; ++r) dst[r*256 + tid] = src[r*256 + tid];
    }
    __syncthreads();
    #pragma unroll
    for (int nt = 0; nt < 8; ++nt)
      #pragma unroll
      for (int kt = 0; kt < 8; ++kt) {
        const bf16x8 bfr = *(const bf16x8*)&bs[((nt*8 + kt)*64 + lane)*8];
        acc[nt] = __builtin_amdgcn_mfma_f32_16x16x32_bf16(afH[kt], bfr, acc[nt], 0, 0, 0);
      }
  }

  #pragma unroll
  for (int nt = 0; nt < 8; ++nt) {
    const int col = nc*128 + nt*16 + ln;
    const float bv = bp1[col];
    #pragma unroll
    for (int reg = 0; reg < 4; ++reg)
      Gterm[(size_t)(row0 + wave*16 + quad*4 + reg) * HID + col] = acc[nt][reg] + bv;
  }
}

// ---------------------------------------------------------------------------
// K2: build x0 (C=256, L=1534) transposed sequence
// ---------------------------------------------------------------------------
__global__ void k_build_x0(const float* __restrict__ nodes,
                           const float* __restrict__ HAts,
                           const bf16* __restrict__ hats,
                           const int* __restrict__ act,
                           float* __restrict__ x0) {
  int t = blockIdx.x * 256 + threadIdx.x;
  int c = blockIdx.y;
  if (t >= LSEQ) return;
  float v;
  if (t == LSEQ - 1) {
    v = nodes[(size_t)(G-1)*D + c];
  } else {
    int r = t / 3, m = t - 3*r;
    if (m == 0)      v = nodes[(size_t)r*D + c];
    else if (m == 1) v = HAts[(size_t)r*D + c];
    else             v = __bfloat162float(hats[(size_t)(r*PER + act[r])*D + c]);
  }
  x0[(size_t)c*LP + t] = v;
}

// ---------------------------------------------------------------------------
// K3: TCN conv partials, split-K over cin (blockIdx.z owns CPB chunks of 32).
// ---------------------------------------------------------------------------
template<int DIL, int CPB, bool HASWD>
__global__ __launch_bounds__(256) void k_tcn4(
    const float* __restrict__ xin,
    const float* __restrict__ W,     // (Cout, Cin, 3)
    const float* __restrict__ Wd,    // (Cout, Cin) or unused
    float* __restrict__ ybuf,        // [NZ][Cout][LP]
    float* __restrict__ rbuf,        // [NZ][Cout][LP] (HASWD only)
    int Cin) {
  __shared__ __align__(16) float xs[32][80];
  __shared__ __align__(16) float wst[3][32][68];
  __shared__ __align__(16) float wds[HASWD ? 32 : 1][HASWD ? 68 : 4];

  const int tid = threadIdx.x;
  const int tt = tid & 15;
  const int cc = tid >> 4;
  const int t0 = blockIdx.x * 64;
  const int o0 = blockIdx.y * 64;
  const int Cout = gridDim.y << 6;

  float acc[4][4], res[4][4];
  #pragma unroll
  for (int it = 0; it < 4; ++it)
    #pragma unroll
    for (int ic = 0; ic < 4; ++ic) { acc[it][ic] = 0.f; res[it][ic] = 0.f; }

  for (int c = 0; c < CPB; ++c) {
    const int i0 = (blockIdx.z * CPB + c) * 32;
    __syncthreads();
    for (int idx = tid; idx < 32*20; idx += 256) {
      int r = idx / 20, j4 = idx - r*20;
      int tp = t0 - 16 + j4*4;
      float4 v;
      if (tp >= 0) v = *(const float4*)&xin[(size_t)(i0 + r)*LP + tp];
      else         v = make_float4(0.f, 0.f, 0.f, 0.f);
      *(float4*)&xs[r][j4*4] = v;
    }
    for (int idx = tid; idx < 64*32; idx += 256) {
      int o = idx >> 5, i = idx & 31;
      const float* wp = &W[((size_t)(o0 + o)*Cin + i0 + i)*3];
      wst[0][i][o] = wp[0];
      wst[1][i][o] = wp[1];
      wst[2][i][o] = wp[2];
      if constexpr (HASWD) wds[i][o] = Wd[(size_t)(o0 + o)*Cin + i0 + i];
    }
    __syncthreads();

    const int base = 16 + tt*4;
    #pragma unroll 2
    for (int i = 0; i < 32; ++i) {
      float4 xv0, xv1, xv2;
      if constexpr (DIL == 1) {
        float4 A = *(const float4*)&xs[i][base - 4];
        float4 B = *(const float4*)&xs[i][base];
        xv0 = make_float4(A.z, A.w, B.x, B.y);
        xv1 = make_float4(A.w, B.x, B.y, B.z);
        xv2 = B;
      } else if constexpr (DIL == 2) {
        float4 A = *(const float4*)&xs[i][base - 4];
        float4 B = *(const float4*)&xs[i][base];
        xv0 = A;
        xv1 = make_float4(A.z, A.w, B.x, B.y);
        xv2 = B;
      } else {
        xv0 = *(const float4*)&xs[i][base - 2*DIL];
        xv1 = *(const float4*)&xs[i][base - DIL];
        xv2 = *(const float4*)&xs[i][base];
      }
      float4 w0 = *(const float4*)&wst[0][i][cc*4];
      float4 w1 = *(const float4*)&wst[1][i][cc*4];
      float4 w2 = *(const float4*)&wst[2][i][cc*4];
      #pragma unroll
      for (int it = 0; it < 4; ++it) {
        float x0 = ((const float*)&xv0)[it];
        float x1 = ((const float*)&xv1)[it];
        float x2 = ((const float*)&xv2)[it];
        #pragma unroll
        for (int ic = 0; ic < 4; ++ic) {
          float a = acc[it][ic];
          a = fmaf(x0, ((const float*)&w0)[ic], a);
          a = fmaf(x1, ((const float*)&w1)[ic], a);
          a = fmaf(x2, ((const float*)&w2)[ic], a);
          acc[it][ic] = a;
        }
      }
      if constexpr (HASWD) {
        float4 wd4 = *(const float4*)&wds[i][cc*4];
        #pragma unroll
        for (int it = 0; it < 4; ++it) {
          float x2 = ((const float*)&xv2)[it];
          #pragma unroll
          for (int ic = 0; ic < 4; ++ic)
            res[it][ic] = fmaf(x2, ((const float*)&wd4)[ic], res[it][ic]);
        }
      }
    }
  }

  const int t = t0 + tt*4;
  #pragma unroll
  for (int ic = 0; ic < 4; ++ic) {
    const int ch = o0 + cc*4 + ic;
    const size_t off = ((size_t)blockIdx.z * Cout + ch) * LP + t;
    float4 v = make_float4(acc[0][ic], acc[1][ic], acc[2][ic], acc[3][ic]);
    *(float4*)&ybuf[off] = v;
    if constexpr (HASWD) {
      float4 rv = make_float4(res[0][ic], res[1][ic], res[2][ic], res[3][ic]);
      *(float4*)&rbuf[off] = rv;
    }
  }
}

// ---------------------------------------------------------------------------
// K3b: reduce NZ partial slices: out = relu(relu(sum_y+b) + res)
// ---------------------------------------------------------------------------
template<int NZ, bool HASWD>
__global__ __launch_bounds__(384) void k_tcn_red(
    const float* __restrict__ ybuf, const float* __restrict__ rbuf,
    const float* __restrict__ xin, const float* __restrict__ b,
    float* __restrict__ xout) {
  const int ch = blockIdx.x;
  const int Cout = gridDim.x;
  const int t = threadIdx.x * 4;
  const size_t stride = (size_t)Cout * LP;
  const size_t base = (size_t)ch * LP + t;

  float4 y = *(const float4*)&ybuf[base];
  #pragma unroll
  for (int z = 1; z < NZ; ++z) {
    float4 u = *(const float4*)&ybuf[base + z*stride];
    y.x += u.x; y.y += u.y; y.z += u.z; y.w += u.w;
  }
  const float bv = b[ch];
  y.x = fmaxf(y.x + bv, 0.f); y.y = fmaxf(y.y + bv, 0.f);
  y.z = fmaxf(y.z + bv, 0.f); y.w = fmaxf(y.w + bv, 0.f);

  float4 r;
  if constexpr (HASWD) {
    r = *(const float4*)&rbuf[base];
    #pragma unroll
    for (int z = 1; z < NZ; ++z) {
      float4 u = *(const float4*)&rbuf[base + z*stride];
      r.x += u.x; r.y += u.y; r.z += u.z; r.w += u.w;
    }
  } else {
    r = *(const float4*)&xin[base];
  }
  float4 v;
  v.x = fmaxf(y.x + r.x, 0.f); v.y = fmaxf(y.y + r.y, 0.f);
  v.z = fmaxf(y.z + r.z, 0.f); v.w = fmaxf(y.w + r.w, 0.f);
  *(float4*)&xout[base] = v;
}

// ---------------------------------------------------------------------------
// K5: MFMA. out[i] = relu(hats[i,:]@Wp1b + Gterm[g,:]) @ Wp2 + bp2
// ---------------------------------------------------------------------------
__global__ __launch_bounds__(256) void k_final_mfma(
    const bf16* __restrict__ hats, const bf16* __restrict__ WBt,
    const float* __restrict__ Gterm, const float* __restrict__ Wp2,
    const float* __restrict__ bp2, float* __restrict__ out) {
  __shared__ __align__(16) unsigned short bs[32768];  // 64 KB
  __shared__ float gs[512];
  __shared__ float w2s[512];

  const int tid = threadIdx.x;
  const int wave = tid >> 6, lane = tid & 63;
  const int ln = lane & 15, quad = lane >> 4;
  const int row0 = blockIdx.x * 64;
  const int g = row0 >> 7;

  gs[tid]        = Gterm[(size_t)g*HID + tid];
  gs[tid + 256]  = Gterm[(size_t)g*HID + tid + 256];
  w2s[tid]       = Wp2[tid];
  w2s[tid + 256] = Wp2[tid + 256];

  bf16x8 afrag[8];
  {
    const uint4* ap = (const uint4*)(hats + (size_t)(row0 + wave*16 + ln) * D);
    #pragma unroll
    for (int kt = 0; kt < 8; ++kt) {
      uint4 t = ap[kt*4 + quad];
      afrag[kt] = *(const bf16x8*)&t;
    }
  }

  float osum[4] = {0.f, 0.f, 0.f, 0.f};

  for (int chunk = 0; chunk < 4; ++chunk) {
    __syncthreads();
    const uint4* src = (const uint4*)(WBt + (size_t)chunk * 32768);
    uint4* dst = (uint4*)bs;
    #pragma unroll
    for (int r = 0; r < 16; ++r) dst[r*256 + tid] = src[r*256 + tid];
    __syncthreads();

    #pragma unroll
    for (int nt = 0; nt < 8; ++nt) {
      f32x4 acc = {0.f, 0.f, 0.f, 0.f};
      #pragma unroll
      for (int kt = 0; kt < 8; ++kt) {
        const bf16x8 bfr = *(const bf16x8*)&bs[((nt*8 + kt)*64 + lane)*8];
        acc = __builtin_amdgcn_mfma_f32_16x16x32_bf16(afrag[kt], bfr, acc, 0, 0, 0);
      }
      int n = chunk*128 + nt*16 + ln;
      float gv = gs[n], wv = w2s[n];
      #pragma unroll
      for (int reg = 0; reg < 4; ++reg) {
        float h = acc[reg] + gv;
        h = h > 0.f ? h : 0.f;
        osum[reg] = fmaf(h, wv, osum[reg]);
      }
    }
  }

  #pragma unroll
  for (int reg = 0; reg < 4; ++reg) {
    float v = osum[reg];
    v += __shfl_xor(v, 1, 64);
    v += __shfl_xor(v, 2, 64);
    v += __shfl_xor(v, 4, 64);
    v += __shfl_xor(v, 8, 64);
    osum[reg] = v;
  }
  if (ln == 0) {
    float b2 = bp2[0];
    #pragma unroll
    for (int reg = 0; reg < 4; ++reg)
      out[row0 + wave*16 + quad*4 + reg] = osum[reg] + b2;
  }
}

// ---------------------------------------------------------------------------
extern "C" void kernel_launch(void* const* d_in, const int* in_sizes, int n_in,
                              void* d_out, int out_size, void* d_ws, size_t ws_size,
                              hipStream_t stream) {
  (void)in_sizes; (void)n_in; (void)out_size; (void)ws_size;
  const float* NEs   = (const float*)d_in[0];
  const float* nodes = (const float*)d_in[1];
  const float* query = (const float*)d_in[2];
  const int*   act   = (const int*)d_in[4];
  const float* Wa    = (const float*)d_in[5];
  const float* ba    = (const float*)d_in[6];
  const float* Wc0   = (const float*)d_in[7];
  const float* bc0   = (const float*)d_in[8];
  const float* Wc1   = (const float*)d_in[9];
  const float* bc1   = (const float*)d_in[10];
  const float* Wd1   = (const float*)d_in[11];
  const float* Wc2   = (const float*)d_in[12];
  const float* bc2   = (const float*)d_in[13];
  const float* Wc3   = (const float*)d_in[14];
  const float* bc3   = (const float*)d_in[15];
  const float* Wd3   = (const float*)d_in[16];
  const float* Wp1   = (const float*)d_in[17];
  const float* bp1   = (const float*)d_in[18];
  const float* Wp2   = (const float*)d_in[19];
  const float* bp2   = (const float*)d_in[20];
  float* out = (float*)d_out;

  char* ws = (char*)d_ws;
  bf16*  hats  = (bf16*)ws;  ws += (size_t)NROW * D * sizeof(bf16);
  float* HAts  = (float*)ws; ws += (size_t)G * D * sizeof(float);
  float* xa    = (float*)ws; ws += (size_t)512 * LP * sizeof(float);
  float* xb    = (float*)ws; ws += (size_t)512 * LP * sizeof(float);
  float* Gterm = (float*)ws; ws += (size_t)G * HID * sizeof(float);
  bf16*  WBt   = (bf16*)ws;  ws += (size_t)D * HID * sizeof(bf16);
  bf16*  WAhi  = (bf16*)ws;  ws += (size_t)D * D * sizeof(bf16);
  bf16*  WAlo  = (bf16*)ws;  ws += (size_t)D * D * sizeof(bf16);
  bf16*  WB1hi = (bf16*)ws;  ws += (size_t)768 * HID * sizeof(bf16);
  bf16*  WB1lo = (bf16*)ws;  ws += (size_t)768 * HID * sizeof(bf16);
  bf16*  Shi   = (bf16*)ws;  ws += (size_t)G * 768 * sizeof(bf16);
  bf16*  Slo   = (bf16*)ws;  ws += (size_t)G * 768 * sizeof(bf16);
  // split-K partial buffers: up to 2048 rows x LP each (12.6 MB each)
  float* P0 = (float*)ws; ws += (size_t)2048 * LP * sizeof(float);
  float* P1 = (float*)ws; ws += (size_t)2048 * LP * sizeof(float);

  k_zeroH<<<G*D/1024, 256, 0, stream>>>((float4*)HAts);
  k_waprep<<<256, 256, 0, stream>>>(Wa, WAhi, WAlo);
  k_hats_mfma<<<NROW/64, 256, 0, stream>>>(NEs, WAhi, WAlo, ba, hats, HAts);
  k_wconv<<<512, 256, 0, stream>>>(Wp1, WBt);
  k_wp1prep<<<1536, 256, 0, stream>>>(Wp1, WB1hi, WB1lo);
  k_build_x0<<<dim3(6, 256), 256, 0, stream>>>(nodes, HAts, hats, act, xa);

  // L0: 256->256, dil=1, NZ=8 (CPB=1): 768 blocks
  k_tcn4<1, 1, false><<<dim3(24, 4, 8), 256, 0, stream>>>(xa, Wc0, nullptr, P0, nullptr, 256);
  k_tcn_red<8, false><<<256, 384, 0, stream>>>(P0, nullptr, xa, bc0, xb);
  // L1: 256->512, dil=2, Wd, NZ=4 (CPB=2): 768 blocks
  k_tcn4<2, 2, true ><<<dim3(24, 8, 4), 256, 0, stream>>>(xb, Wc1, Wd1, P0, P1, 256);
  k_tcn_red<4, true ><<<512, 384, 0, stream>>>(P0, P1, xb, bc1, xa);
  // L2: 512->512, dil=4, NZ=4 (CPB=4): 768 blocks
  k_tcn4<4, 4, false><<<dim3(24, 8, 4), 256, 0, stream>>>(xa, Wc2, nullptr, P0, nullptr, 512);
  k_tcn_red<4, false><<<512, 384, 0, stream>>>(P0, nullptr, xa, bc2, xb);
  // L3: 512->256, dil=8, Wd, NZ=8 (CPB=2): 768 blocks
  k_tcn4<8, 2, true ><<<dim3(24, 4, 8), 256, 0, stream>>>(xb, Wc3, Wd3, P0, P1, 512);
  k_tcn_red<8, true ><<<256, 384, 0, stream>>>(P0, P1, xb, bc3, xa);

  k_sprep<<<dim3(3, G), 256, 0, stream>>>(query, HAts, xa, Shi, Slo);
  k_gterm_mfma<<<dim3(4, 8), 256, 0, stream>>>(Shi, Slo, WB1hi, WB1lo, bp1, Gterm);
  k_final_mfma<<<NROW/64, 256, 0, stream>>>(hats, WBt, Gterm, Wp2, bp2, out);
}

// Round 6
// 355.547 us; speedup vs baseline: 1.0492x; 1.0492x over previous
//
#include <hip/hip_runtime.h>
#include <hip/hip_bf16.h>

#define D 256
#define G 512
#define PER 128
#define NROW (G*PER)   // 65536
#define LSEQ 1534
#define LP 1536
#define HID 512

typedef __hip_bfloat16 bf16;
typedef __attribute__((ext_vector_type(8))) short bf16x8;
typedef __attribute__((ext_vector_type(4))) float f32x4;

// MFMA B layout (conflict-free): within each 64KB chunk, fragment block
// (nt,kt) occupies 1KB; 16B unit index within block = lane = quad*16 + ln.
// Element (k,n): nt=(n>>4)&7, kt=k>>5, quad=(k>>3)&3, ln=n&15, e=k&7.

// ---------------------------------------------------------------------------
// K-prep (fused): waprep (blocks 0..255), wconv (256..767), wp1prep (768..2303)
// ---------------------------------------------------------------------------
__global__ __launch_bounds__(256) void k_prep(
    const float* __restrict__ Wa, bf16* __restrict__ WAhi, bf16* __restrict__ WAlo,
    const float* __restrict__ Wp1, bf16* __restrict__ WBt,
    bf16* __restrict__ WB1hi, bf16* __restrict__ WB1lo) {
  const int b = blockIdx.x, tid = threadIdx.x;
  if (b < 256) {
    // Wa (256x256) -> hi/lo MFMA tiles
    int id = b * 256 + tid;          // id = k*256 + n
    int k = id >> 8, n = id & 255;
    float v = Wa[(size_t)k * D + n];
    bf16 h = __float2bfloat16(v);
    bf16 l = __float2bfloat16(v - __bfloat162float(h));
    int dst = (n >> 7) * 32768
            + (((((n >> 4) & 7) * 8 + (k >> 5)) * 64 + ((k >> 3) & 3) * 16 + (n & 15)) * 8)
            + (k & 7);
    WAhi[dst] = h;
    WAlo[dst] = l;
  } else if (b < 768) {
    // Wp1 rows 768..1023 -> WBt
    int id = (b - 256) * 256 + tid;  // id = k*512 + n
    int k = id >> 9, n = id & 511;
    float v = Wp1[(size_t)(768 + k) * HID + n];
    int dst = (n >> 7) * 32768
            + (((((n >> 4) & 7) * 8 + (k >> 5)) * 64 + ((k >> 3) & 3) * 16 + (n & 15)) * 8)
            + (k & 7);
    WBt[dst] = __float2bfloat16(v);
  } else {
    // Wp1 rows 0..767 -> hi/lo tiles (tile = nc*3 + kc)
    int id = (b - 768) * 256 + tid;  // id = k*512 + n, k<768
    int k = id >> 9, n = id & 511;
    float v = Wp1[(size_t)k * HID + n];
    bf16 h = __float2bfloat16(v);
    bf16 l = __float2bfloat16(v - __bfloat162float(h));
    int kc = k >> 8, kr = k & 255;
    int nc = n >> 7, nr = n & 127;
    int dst = (nc*3 + kc) * 32768
            + ((((nr >> 4) * 8 + (kr >> 5)) * 64 + ((kr >> 3) & 3) * 16 + (nr & 15)) * 8)
            + (kr & 7);
    WB1hi[dst] = h;
    WB1lo[dst] = l;
  }
}

// ---------------------------------------------------------------------------
// K1: hats = relu(NEs @ Wa + ba) via split-bf16 MFMA (AhiBhi+AloBhi+AhiBlo).
// 128 rows/block (= one group), 512 threads / 8 waves. B staged 64KB/phase.
// HAts written directly (no atomics). LDS-bounce coalesced bf16 stores.
// ---------------------------------------------------------------------------
__global__ __launch_bounds__(512) void k_hats_mfma(
    const float* __restrict__ NEs, const bf16* __restrict__ WAhi,
    const bf16* __restrict__ WAlo, const float* __restrict__ ba,
    bf16* __restrict__ hats, float* __restrict__ HAts) {
  __shared__ __align__(16) unsigned short bs[36864];  // 72 KB (stage 64KB / bounce 70KB)
  __shared__ float wsmax[8][128];

  const int tid = threadIdx.x;
  const int wave = tid >> 6, lane = tid & 63;
  const int ln = lane & 15, quad = lane >> 4;
  const int row0 = blockIdx.x * 128;
  const int g = blockIdx.x;

  bf16x8 afH[8], afL[8];
  {
    const float4* ap = (const float4*)(NEs + (size_t)(row0 + wave*16 + ln) * D);
    #pragma unroll
    for (int kt = 0; kt < 8; ++kt) {
      float4 x0 = ap[kt*8 + quad*2];
      float4 x1 = ap[kt*8 + quad*2 + 1];
      float xv[8] = {x0.x, x0.y, x0.z, x0.w, x1.x, x1.y, x1.z, x1.w};
      bf16x8 hv, lv;
      #pragma unroll
      for (int e = 0; e < 8; ++e) {
        bf16 h = __float2bfloat16(xv[e]);
        bf16 l = __float2bfloat16(xv[e] - __bfloat162float(h));
        hv[e] = *(short*)&h;
        lv[e] = *(short*)&l;
      }
      afH[kt] = hv;
      afL[kt] = lv;
    }
  }

  float* bsf = (float*)bs;   // bounce view: [128][140] floats (70 KB)

  for (int chunk = 0; chunk < 2; ++chunk) {
    f32x4 acc[8];
    #pragma unroll
    for (int nt = 0; nt < 8; ++nt) acc[nt] = (f32x4){0.f, 0.f, 0.f, 0.f};

    __syncthreads();
    {
      const uint4* src = (const uint4*)(WAhi + (size_t)chunk * 32768);
      uint4* dst = (uint4*)bs;
      #pragma unroll
      for (int r = 0; r < 8; ++r) dst[r*512 + tid] = src[r*512 + tid];
    }
    __syncthreads();
    #pragma unroll
    for (int nt = 0; nt < 8; ++nt)
      #pragma unroll
      for (int kt = 0; kt < 8; ++kt) {
        const bf16x8 bfr = *(const bf16x8*)&bs[((nt*8 + kt)*64 + lane)*8];
        acc[nt] = __builtin_amdgcn_mfma_f32_16x16x32_bf16(afH[kt], bfr, acc[nt], 0, 0, 0);
        acc[nt] = __builtin_amdgcn_mfma_f32_16x16x32_bf16(afL[kt], bfr, acc[nt], 0, 0, 0);
      }

    __syncthreads();
    {
      const uint4* src = (const uint4*)(WAlo + (size_t)chunk * 32768);
      uint4* dst = (uint4*)bs;
      #pragma unroll
      for (int r = 0; r < 8; ++r) dst[r*512 + tid] = src[r*512 + tid];
    }
    __syncthreads();
    #pragma unroll
    for (int nt = 0; nt < 8; ++nt)
      #pragma unroll
      for (int kt = 0; kt < 8; ++kt) {
        const bf16x8 bfr = *(const bf16x8*)&bs[((nt*8 + kt)*64 + lane)*8];
        acc[nt] = __builtin_amdgcn_mfma_f32_16x16x32_bf16(afH[kt], bfr, acc[nt], 0, 0, 0);
      }

    __syncthreads();
    #pragma unroll
    for (int nt = 0; nt < 8; ++nt) {
      const float bv = ba[chunk*128 + nt*16 + ln];
      float m = 0.f;
      #pragma unroll
      for (int reg = 0; reg < 4; ++reg) {
        float h = acc[nt][reg] + bv;
        h = h > 0.f ? h : 0.f;
        bsf[(wave*16 + quad*4 + reg)*140 + nt*16 + ln] = h;
        m = fmaxf(m, h);
      }
      m = fmaxf(m, __shfl_xor(m, 16, 64));
      m = fmaxf(m, __shfl_xor(m, 32, 64));
      if (quad == 0) wsmax[wave][nt*16 + ln] = m;
    }
    __syncthreads();
    {
      const int row = tid >> 2, q4 = tid & 3;
      const float* rp = &bsf[row*140 + q4*32];
      bf16* gp = hats + (size_t)(row0 + row) * D + chunk*128 + q4*32;
      #pragma unroll
      for (int s = 0; s < 4; ++s) {
        float4 v0 = *(const float4*)&rp[s*8];
        float4 v1 = *(const float4*)&rp[s*8 + 4];
        float vv[8] = {v0.x, v0.y, v0.z, v0.w, v1.x, v1.y, v1.z, v1.w};
        bf16x8 pk;
        #pragma unroll
        for (int e = 0; e < 8; ++e) {
          bf16 b = __float2bfloat16(vv[e]);
          pk[e] = *(short*)&b;
        }
        *(bf16x8*)(gp + s*8) = pk;
      }
    }
    if (tid < 128) {
      float m = wsmax[0][tid];
      #pragma unroll
      for (int w = 1; w < 8; ++w) m = fmaxf(m, wsmax[w][tid]);
      HAts[(size_t)g*D + chunk*128 + tid] = m;
    }
  }
}

// ---------------------------------------------------------------------------
// K-sprep: S = [query | hs | HAts] (512 x 768) -> row-major bf16 hi/lo
// ---------------------------------------------------------------------------
__global__ void k_sprep(const float* __restrict__ query,
                        const float* __restrict__ HAts,
                        const float* __restrict__ xfin,
                        bf16* __restrict__ Shi, bf16* __restrict__ Slo) {
  int m = blockIdx.x * 256 + threadIdx.x;   // 0..767
  int g = blockIdx.y;
  float v;
  if (m < 256)      v = query[(size_t)g*D + m];
  else if (m < 512) v = xfin[(size_t)(m - 256)*LP + 3*g];
  else              v = HAts[(size_t)g*D + (m - 512)];
  bf16 h = __float2bfloat16(v);
  bf16 l = __float2bfloat16(v - __bfloat162float(h));
  Shi[(size_t)g*768 + m] = h;
  Slo[(size_t)g*768 + m] = l;
}

// ---------------------------------------------------------------------------
// K4: Gterm = S @ Wp1[0:768] + bp1 via split-bf16 MFMA.
// ---------------------------------------------------------------------------
__global__ __launch_bounds__(256) void k_gterm_mfma(
    const bf16* __restrict__ Shi, const bf16* __restrict__ Slo,
    const bf16* __restrict__ WB1hi, const bf16* __restrict__ WB1lo,
    const float* __restrict__ bp1, float* __restrict__ Gterm) {
  __shared__ __align__(16) unsigned short bs[32768];  // 64 KB

  const int tid = threadIdx.x;
  const int wave = tid >> 6, lane = tid & 63;
  const int ln = lane & 15, quad = lane >> 4;
  const int nc = blockIdx.x;
  const int row0 = blockIdx.y * 64;

  f32x4 acc[8];
  #pragma unroll
  for (int nt = 0; nt < 8; ++nt) acc[nt] = (f32x4){0.f, 0.f, 0.f, 0.f};

  const uint4* ahp = (const uint4*)(Shi + (size_t)(row0 + wave*16 + ln) * 768);
  const uint4* alp = (const uint4*)(Slo + (size_t)(row0 + wave*16 + ln) * 768);

  for (int kc = 0; kc < 3; ++kc) {
    bf16x8 afH[8], afL[8];
    #pragma unroll
    for (int kt = 0; kt < 8; ++kt) {
      uint4 th = ahp[kc*32 + kt*4 + quad];
      uint4 tl = alp[kc*32 + kt*4 + quad];
      afH[kt] = *(const bf16x8*)&th;
      afL[kt] = *(const bf16x8*)&tl;
    }

    __syncthreads();
    {
      const uint4* src = (const uint4*)(WB1hi + (size_t)(nc*3 + kc) * 32768);
      uint4* dst = (uint4*)bs;
      #pragma unroll
      for (int r = 0; r < 16; ++r) dst[r*256 + tid] = src[r*256 + tid];
    }
    __syncthreads();
    #pragma unroll
    for (int nt = 0; nt < 8; ++nt)
      #pragma unroll
      for (int kt = 0; kt < 8; ++kt) {
        const bf16x8 bfr = *(const bf16x8*)&bs[((nt*8 + kt)*64 + lane)*8];
        acc[nt] = __builtin_amdgcn_mfma_f32_16x16x32_bf16(afH[kt], bfr, acc[nt], 0, 0, 0);
        acc[nt] = __builtin_amdgcn_mfma_f32_16x16x32_bf16(afL[kt], bfr, acc[nt], 0, 0, 0);
      }

    __syncthreads();
    {
      const uint4* src = (const uint4*)(WB1lo + (size_t)(nc*3 + kc) * 32768);
      uint4* dst = (uint4*)bs;
      #pragma unroll
      for (int r = 0; r < 16; ++r) dst[r*256 + tid] = src[r*256 + tid];
    }
    __syncthreads();
    #pragma unroll
    for (int nt = 0; nt < 8; ++nt)
      #pragma unroll
      for (int kt = 0; kt < 8; ++kt) {
        const bf16x8 bfr = *(const bf16x8*)&bs[((nt*8 + kt)*64 + lane)*8];
        acc[nt] = __builtin_amdgcn_mfma_f32_16x16x32_bf16(afH[kt], bfr, acc[nt], 0, 0, 0);
      }
  }

  #pragma unroll
  for (int nt = 0; nt < 8; ++nt) {
    const int col = nc*128 + nt*16 + ln;
    const float bv = bp1[col];
    #pragma unroll
    for (int reg = 0; reg < 4; ++reg)
      Gterm[(size_t)(row0 + wave*16 + quad*4 + reg) * HID + col] = acc[nt][reg] + bv;
  }
}

// ---------------------------------------------------------------------------
// K2: build x0 (C=256, L=1534) transposed sequence
// ---------------------------------------------------------------------------
__global__ void k_build_x0(const float* __restrict__ nodes,
                           const float* __restrict__ HAts,
                           const bf16* __restrict__ hats,
                           const int* __restrict__ act,
                           float* __restrict__ x0) {
  int t = blockIdx.x * 256 + threadIdx.x;
  int c = blockIdx.y;
  if (t >= LSEQ) return;
  float v;
  if (t == LSEQ - 1) {
    v = nodes[(size_t)(G-1)*D + c];
  } else {
    int r = t / 3, m = t - 3*r;
    if (m == 0)      v = nodes[(size_t)r*D + c];
    else if (m == 1) v = HAts[(size_t)r*D + c];
    else             v = __bfloat162float(hats[(size_t)(r*PER + act[r])*D + c]);
  }
  x0[(size_t)c*LP + t] = v;
}

// ---------------------------------------------------------------------------
// K3: TCN conv partials, split-K over cin (blockIdx.z owns CPB chunks of 32).
// ---------------------------------------------------------------------------
template<int DIL, int CPB, bool HASWD>
__global__ __launch_bounds__(256) void k_tcn4(
    const float* __restrict__ xin,
    const float* __restrict__ W,     // (Cout, Cin, 3)
    const float* __restrict__ Wd,    // (Cout, Cin) or unused
    float* __restrict__ ybuf,        // [NZ][Cout][LP]
    float* __restrict__ rbuf,        // [NZ][Cout][LP] (HASWD only)
    int Cin) {
  __shared__ __align__(16) float xs[32][80];
  __shared__ __align__(16) float wst[3][32][68];
  __shared__ __align__(16) float wds[HASWD ? 32 : 1][HASWD ? 68 : 4];

  const int tid = threadIdx.x;
  const int tt = tid & 15;
  const int cc = tid >> 4;
  const int t0 = blockIdx.x * 64;
  const int o0 = blockIdx.y * 64;
  const int Cout = gridDim.y << 6;

  float acc[4][4], res[4][4];
  #pragma unroll
  for (int it = 0; it < 4; ++it)
    #pragma unroll
    for (int ic = 0; ic < 4; ++ic) { acc[it][ic] = 0.f; res[it][ic] = 0.f; }

  for (int c = 0; c < CPB; ++c) {
    const int i0 = (blockIdx.z * CPB + c) * 32;
    __syncthreads();
    for (int idx = tid; idx < 32*20; idx += 256) {
      int r = idx / 20, j4 = idx - r*20;
      int tp = t0 - 16 + j4*4;
      float4 v;
      if (tp >= 0) v = *(const float4*)&xin[(size_t)(i0 + r)*LP + tp];
      else         v = make_float4(0.f, 0.f, 0.f, 0.f);
      *(float4*)&xs[r][j4*4] = v;
    }
    for (int idx = tid; idx < 64*32; idx += 256) {
      int o = idx >> 5, i = idx & 31;
      const float* wp = &W[((size_t)(o0 + o)*Cin + i0 + i)*3];
      wst[0][i][o] = wp[0];
      wst[1][i][o] = wp[1];
      wst[2][i][o] = wp[2];
      if constexpr (HASWD) wds[i][o] = Wd[(size_t)(o0 + o)*Cin + i0 + i];
    }
    __syncthreads();

    const int base = 16 + tt*4;
    #pragma unroll 2
    for (int i = 0; i < 32; ++i) {
      float4 xv0, xv1, xv2;
      if constexpr (DIL == 1) {
        float4 A = *(const float4*)&xs[i][base - 4];
        float4 B = *(const float4*)&xs[i][base];
        xv0 = make_float4(A.z, A.w, B.x, B.y);
        xv1 = make_float4(A.w, B.x, B.y, B.z);
        xv2 = B;
      } else if constexpr (DIL == 2) {
        float4 A = *(const float4*)&xs[i][base - 4];
        float4 B = *(const float4*)&xs[i][base];
        xv0 = A;
        xv1 = make_float4(A.z, A.w, B.x, B.y);
        xv2 = B;
      } else {
        xv0 = *(const float4*)&xs[i][base - 2*DIL];
        xv1 = *(const float4*)&xs[i][base - DIL];
        xv2 = *(const float4*)&xs[i][base];
      }
      float4 w0 = *(const float4*)&wst[0][i][cc*4];
      float4 w1 = *(const float4*)&wst[1][i][cc*4];
      float4 w2 = *(const float4*)&wst[2][i][cc*4];
      #pragma unroll
      for (int it = 0; it < 4; ++it) {
        float x0 = ((const float*)&xv0)[it];
        float x1 = ((const float*)&xv1)[it];
        float x2 = ((const float*)&xv2)[it];
        #pragma unroll
        for (int ic = 0; ic < 4; ++ic) {
          float a = acc[it][ic];
          a = fmaf(x0, ((const float*)&w0)[ic], a);
          a = fmaf(x1, ((const float*)&w1)[ic], a);
          a = fmaf(x2, ((const float*)&w2)[ic], a);
          acc[it][ic] = a;
        }
      }
      if constexpr (HASWD) {
        float4 wd4 = *(const float4*)&wds[i][cc*4];
        #pragma unroll
        for (int it = 0; it < 4; ++it) {
          float x2 = ((const float*)&xv2)[it];
          #pragma unroll
          for (int ic = 0; ic < 4; ++ic)
            res[it][ic] = fmaf(x2, ((const float*)&wd4)[ic], res[it][ic]);
        }
      }
    }
  }

  const int t = t0 + tt*4;
  #pragma unroll
  for (int ic = 0; ic < 4; ++ic) {
    const int ch = o0 + cc*4 + ic;
    const size_t off = ((size_t)blockIdx.z * Cout + ch) * LP + t;
    float4 v = make_float4(acc[0][ic], acc[1][ic], acc[2][ic], acc[3][ic]);
    *(float4*)&ybuf[off] = v;
    if constexpr (HASWD) {
      float4 rv = make_float4(res[0][ic], res[1][ic], res[2][ic], res[3][ic]);
      *(float4*)&rbuf[off] = rv;
    }
  }
}

// ---------------------------------------------------------------------------
// K3b: reduce NZ partial slices: out = relu(relu(sum_y+b) + res)
// ---------------------------------------------------------------------------
template<int NZ, bool HASWD>
__global__ __launch_bounds__(384) void k_tcn_red(
    const float* __restrict__ ybuf, const float* __restrict__ rbuf,
    const float* __restrict__ xin, const float* __restrict__ b,
    float* __restrict__ xout) {
  const int ch = blockIdx.x;
  const int Cout = gridDim.x;
  const int t = threadIdx.x * 4;
  const size_t stride = (size_t)Cout * LP;
  const size_t base = (size_t)ch * LP + t;

  float4 y = *(const float4*)&ybuf[base];
  #pragma unroll
  for (int z = 1; z < NZ; ++z) {
    float4 u = *(const float4*)&ybuf[base + z*stride];
    y.x += u.x; y.y += u.y; y.z += u.z; y.w += u.w;
  }
  const float bv = b[ch];
  y.x = fmaxf(y.x + bv, 0.f); y.y = fmaxf(y.y + bv, 0.f);
  y.z = fmaxf(y.z + bv, 0.f); y.w = fmaxf(y.w + bv, 0.f);

  float4 r;
  if constexpr (HASWD) {
    r = *(const float4*)&rbuf[base];
    #pragma unroll
    for (int z = 1; z < NZ; ++z) {
      float4 u = *(const float4*)&rbuf[base + z*stride];
      r.x += u.x; r.y += u.y; r.z += u.z; r.w += u.w;
    }
  } else {
    r = *(const float4*)&xin[base];
  }
  float4 v;
  v.x = fmaxf(y.x + r.x, 0.f); v.y = fmaxf(y.y + r.y, 0.f);
  v.z = fmaxf(y.z + r.z, 0.f); v.w = fmaxf(y.w + r.w, 0.f);
  *(float4*)&xout[base] = v;
}

// ---------------------------------------------------------------------------
// K5: out[i] = relu(hats[i,:]@Wp1b + Gterm[g,:]) @ Wp2 + bp2.
// 128 rows/block (= one group), 512 threads / 8 waves.
// ---------------------------------------------------------------------------
__global__ __launch_bounds__(512) void k_final_mfma(
    const bf16* __restrict__ hats, const bf16* __restrict__ WBt,
    const float* __restrict__ Gterm, const float* __restrict__ Wp2,
    const float* __restrict__ bp2, float* __restrict__ out) {
  __shared__ __align__(16) unsigned short bs[32768];  // 64 KB
  __shared__ float gs[512];
  __shared__ float w2s[512];

  const int tid = threadIdx.x;
  const int wave = tid >> 6, lane = tid & 63;
  const int ln = lane & 15, quad = lane >> 4;
  const int row0 = blockIdx.x * 128;
  const int g = blockIdx.x;

  gs[tid]  = Gterm[(size_t)g*HID + tid];
  w2s[tid] = Wp2[tid];

  bf16x8 afrag[8];
  {
    const uint4* ap = (const uint4*)(hats + (size_t)(row0 + wave*16 + ln) * D);
    #pragma unroll
    for (int kt = 0; kt < 8; ++kt) {
      uint4 t = ap[kt*4 + quad];
      afrag[kt] = *(const bf16x8*)&t;
    }
  }

  float osum[4] = {0.f, 0.f, 0.f, 0.f};

  for (int chunk = 0; chunk < 4; ++chunk) {
    __syncthreads();
    const uint4* src = (const uint4*)(WBt + (size_t)chunk * 32768);
    uint4* dst = (uint4*)bs;
    #pragma unroll
    for (int r = 0; r < 8; ++r) dst[r*512 + tid] = src[r*512 + tid];
    __syncthreads();

    #pragma unroll
    for (int nt = 0; nt < 8; ++nt) {
      f32x4 acc = {0.f, 0.f, 0.f, 0.f};
      #pragma unroll
      for (int kt = 0; kt < 8; ++kt) {
        const bf16x8 bfr = *(const bf16x8*)&bs[((nt*8 + kt)*64 + lane)*8];
        acc = __builtin_amdgcn_mfma_f32_16x16x32_bf16(afrag[kt], bfr, acc, 0, 0, 0);
      }
      int n = chunk*128 + nt*16 + ln;
      float gv = gs[n], wv = w2s[n];
      #pragma unroll
      for (int reg = 0; reg < 4; ++reg) {
        float h = acc[reg] + gv;
        h = h > 0.f ? h : 0.f;
        osum[reg] = fmaf(h, wv, osum[reg]);
      }
    }
  }

  #pragma unroll
  for (int reg = 0; reg < 4; ++reg) {
    float v = osum[reg];
    v += __shfl_xor(v, 1, 64);
    v += __shfl_xor(v, 2, 64);
    v += __shfl_xor(v, 4, 64);
    v += __shfl_xor(v, 8, 64);
    osum[reg] = v;
  }
  if (ln == 0) {
    float b2 = bp2[0];
    #pragma unroll
    for (int reg = 0; reg < 4; ++reg)
      out[row0 + wave*16 + quad*4 + reg] = osum[reg] + b2;
  }
}

// ---------------------------------------------------------------------------
extern "C" void kernel_launch(void* const* d_in, const int* in_sizes, int n_in,
                              void* d_out, int out_size, void* d_ws, size_t ws_size,
                              hipStream_t stream) {
  (void)in_sizes; (void)n_in; (void)out_size; (void)ws_size;
  const float* NEs   = (const float*)d_in[0];
  const float* nodes = (const float*)d_in[1];
  const float* query = (const float*)d_in[2];
  const int*   act   = (const int*)d_in[4];
  const float* Wa    = (const float*)d_in[5];
  const float* ba    = (const float*)d_in[6];
  const float* Wc0   = (const float*)d_in[7];
  const float* bc0   = (const float*)d_in[8];
  const float* Wc1   = (const float*)d_in[9];
  const float* bc1   = (const float*)d_in[10];
  const float* Wd1   = (const float*)d_in[11];
  const float* Wc2   = (const float*)d_in[12];
  const float* bc2   = (const float*)d_in[13];
  const float* Wc3   = (const float*)d_in[14];
  const float* bc3   = (const float*)d_in[15];
  const float* Wd3   = (const float*)d_in[16];
  const float* Wp1   = (const float*)d_in[17];
  const float* bp1   = (const float*)d_in[18];
  const float* Wp2   = (const float*)d_in[19];
  const float* bp2   = (const float*)d_in[20];
  float* out = (float*)d_out;

  char* ws = (char*)d_ws;
  bf16*  hats  = (bf16*)ws;  ws += (size_t)NROW * D * sizeof(bf16);
  float* HAts  = (float*)ws; ws += (size_t)G * D * sizeof(float);
  float* xa    = (float*)ws; ws += (size_t)512 * LP * sizeof(float);
  float* xb    = (float*)ws; ws += (size_t)512 * LP * sizeof(float);
  float* Gterm = (float*)ws; ws += (size_t)G * HID * sizeof(float);
  bf16*  WBt   = (bf16*)ws;  ws += (size_t)D * HID * sizeof(bf16);
  bf16*  WAhi  = (bf16*)ws;  ws += (size_t)D * D * sizeof(bf16);
  bf16*  WAlo  = (bf16*)ws;  ws += (size_t)D * D * sizeof(bf16);
  bf16*  WB1hi = (bf16*)ws;  ws += (size_t)768 * HID * sizeof(bf16);
  bf16*  WB1lo = (bf16*)ws;  ws += (size_t)768 * HID * sizeof(bf16);
  bf16*  Shi   = (bf16*)ws;  ws += (size_t)G * 768 * sizeof(bf16);
  bf16*  Slo   = (bf16*)ws;  ws += (size_t)G * 768 * sizeof(bf16);
  // split-K partial buffers: up to 2048 rows x LP each (12.6 MB each)
  float* P0 = (float*)ws; ws += (size_t)2048 * LP * sizeof(float);
  float* P1 = (float*)ws; ws += (size_t)2048 * LP * sizeof(float);

  k_prep<<<2304, 256, 0, stream>>>(Wa, WAhi, WAlo, Wp1, WBt, WB1hi, WB1lo);
  k_hats_mfma<<<G, 512, 0, stream>>>(NEs, WAhi, WAlo, ba, hats, HAts);
  k_build_x0<<<dim3(6, 256), 256, 0, stream>>>(nodes, HAts, hats, act, xa);

  // L0: 256->256, dil=1, NZ=8 (CPB=1): 768 blocks
  k_tcn4<1, 1, false><<<dim3(24, 4, 8), 256, 0, stream>>>(xa, Wc0, nullptr, P0, nullptr, 256);
  k_tcn_red<8, false><<<256, 384, 0, stream>>>(P0, nullptr, xa, bc0, xb);
  // L1: 256->512, dil=2, Wd, NZ=4 (CPB=2): 768 blocks
  k_tcn4<2, 2, true ><<<dim3(24, 8, 4), 256, 0, stream>>>(xb, Wc1, Wd1, P0, P1, 256);
  k_tcn_red<4, true ><<<512, 384, 0, stream>>>(P0, P1, xb, bc1, xa);
  // L2: 512->512, dil=4, NZ=4 (CPB=4): 768 blocks
  k_tcn4<4, 4, false><<<dim3(24, 8, 4), 256, 0, stream>>>(xa, Wc2, nullptr, P0, nullptr, 512);
  k_tcn_red<4, false><<<512, 384, 0, stream>>>(P0, nullptr, xa, bc2, xb);
  // L3: 512->256, dil=8, Wd, NZ=8 (CPB=2): 768 blocks
  k_tcn4<8, 2, true ><<<dim3(24, 4, 8), 256, 0, stream>>>(xb, Wc3, Wd3, P0, P1, 512);
  k_tcn_red<8, true ><<<256, 384, 0, stream>>>(P0, P1, xb, bc3, xa);

  k_sprep<<<dim3(3, G), 256, 0, stream>>>(query, HAts, xa, Shi, Slo);
  k_gterm_mfma<<<dim3(4, 8), 256, 0, stream>>>(Shi, Slo, WB1hi, WB1lo, bp1, Gterm);
  k_final_mfma<<<G, 512, 0, stream>>>(hats, WBt, Gterm, Wp2, bp2, out);
}

// Round 7
// 354.448 us; speedup vs baseline: 1.0524x; 1.0031x over previous
//
#include <hip/hip_runtime.h>
#include <hip/hip_bf16.h>

#define D 256
#define G 512
#define PER 128
#define NROW (G*PER)   // 65536
#define LSEQ 1534
#define LP 1536
#define HID 512

typedef __hip_bfloat16 bf16;
typedef __attribute__((ext_vector_type(8))) short bf16x8;
typedef __attribute__((ext_vector_type(4))) float f32x4;

// MFMA B layout (conflict-free): within each 64KB chunk, fragment block
// (nt,kt) occupies 1KB; 16B unit index within block = lane = quad*16 + ln.
// Element (k,n): nt=(n>>4)&7, kt=k>>5, quad=(k>>3)&3, ln=n&15, e=k&7.

// ---------------------------------------------------------------------------
// K-prep (fused): waprep (blocks 0..255), wconv (256..767), wp1prep (768..2303)
// ---------------------------------------------------------------------------
__global__ __launch_bounds__(256) void k_prep(
    const float* __restrict__ Wa, bf16* __restrict__ WAhi, bf16* __restrict__ WAlo,
    const float* __restrict__ Wp1, bf16* __restrict__ WBt,
    bf16* __restrict__ WB1hi, bf16* __restrict__ WB1lo) {
  const int b = blockIdx.x, tid = threadIdx.x;
  if (b < 256) {
    int id = b * 256 + tid;          // id = k*256 + n
    int k = id >> 8, n = id & 255;
    float v = Wa[(size_t)k * D + n];
    bf16 h = __float2bfloat16(v);
    bf16 l = __float2bfloat16(v - __bfloat162float(h));
    int dst = (n >> 7) * 32768
            + (((((n >> 4) & 7) * 8 + (k >> 5)) * 64 + ((k >> 3) & 3) * 16 + (n & 15)) * 8)
            + (k & 7);
    WAhi[dst] = h;
    WAlo[dst] = l;
  } else if (b < 768) {
    int id = (b - 256) * 256 + tid;  // id = k*512 + n
    int k = id >> 9, n = id & 511;
    float v = Wp1[(size_t)(768 + k) * HID + n];
    int dst = (n >> 7) * 32768
            + (((((n >> 4) & 7) * 8 + (k >> 5)) * 64 + ((k >> 3) & 3) * 16 + (n & 15)) * 8)
            + (k & 7);
    WBt[dst] = __float2bfloat16(v);
  } else {
    int id = (b - 768) * 256 + tid;  // id = k*512 + n, k<768
    int k = id >> 9, n = id & 511;
    float v = Wp1[(size_t)k * HID + n];
    bf16 h = __float2bfloat16(v);
    bf16 l = __float2bfloat16(v - __bfloat162float(h));
    int kc = k >> 8, kr = k & 255;
    int nc = n >> 7, nr = n & 127;
    int dst = (nc*3 + kc) * 32768
            + ((((nr >> 4) * 8 + (kr >> 5)) * 64 + ((kr >> 3) & 3) * 16 + (nr & 15)) * 8)
            + (kr & 7);
    WB1hi[dst] = h;
    WB1lo[dst] = l;
  }
}

// ---------------------------------------------------------------------------
// K1: hats = relu(NEs @ Wa + ba) via split-bf16 MFMA (AhiBhi+AloBhi+AhiBlo).
// 256 threads / 4 waves, 128 rows/block (= one group), 2 row-tiles per wave:
// each B-fragment ds_read feeds 2-4 MFMAs (LDS-read amortization).
// Epilogue bounce in 2x 64-row sub-passes reusing the stage buffer.
// ---------------------------------------------------------------------------
__global__ __launch_bounds__(256, 2) void k_hats_mfma(
    const float* __restrict__ NEs, const bf16* __restrict__ WAhi,
    const bf16* __restrict__ WAlo, const float* __restrict__ ba,
    bf16* __restrict__ hats, float* __restrict__ HAts) {
  __shared__ __align__(16) unsigned short bs[32768];  // 64 KB (stage / bounce)
  __shared__ float wsmax[8][128];

  const int tid = threadIdx.x;
  const int wave = tid >> 6, lane = tid & 63;
  const int ln = lane & 15, quad = lane >> 4;
  const int row0 = blockIdx.x * 128;
  const int g = blockIdx.x;

  // A fragments: 2 row-tiles per wave; tile t covers rows (t*4+wave)*16 + ...
  bf16x8 afH[2][8], afL[2][8];
  #pragma unroll
  for (int t = 0; t < 2; ++t) {
    const float4* ap = (const float4*)(NEs + (size_t)(row0 + (t*4 + wave)*16 + ln) * D);
    #pragma unroll
    for (int kt = 0; kt < 8; ++kt) {
      float4 x0 = ap[kt*8 + quad*2];
      float4 x1 = ap[kt*8 + quad*2 + 1];
      float xv[8] = {x0.x, x0.y, x0.z, x0.w, x1.x, x1.y, x1.z, x1.w};
      bf16x8 hv, lv;
      #pragma unroll
      for (int e = 0; e < 8; ++e) {
        bf16 h = __float2bfloat16(xv[e]);
        bf16 l = __float2bfloat16(xv[e] - __bfloat162float(h));
        hv[e] = *(short*)&h;
        lv[e] = *(short*)&l;
      }
      afH[t][kt] = hv;
      afL[t][kt] = lv;
    }
  }

  float* bsf = (float*)bs;   // bounce view: [64][140] floats (35 KB)

  for (int chunk = 0; chunk < 2; ++chunk) {
    f32x4 acc[2][8];
    #pragma unroll
    for (int t = 0; t < 2; ++t)
      #pragma unroll
      for (int nt = 0; nt < 8; ++nt) acc[t][nt] = (f32x4){0.f, 0.f, 0.f, 0.f};

    __syncthreads();
    {
      const uint4* src = (const uint4*)(WAhi + (size_t)chunk * 32768);
      uint4* dst = (uint4*)bs;
      #pragma unroll
      for (int r = 0; r < 16; ++r) dst[r*256 + tid] = src[r*256 + tid];
    }
    __syncthreads();
    #pragma unroll
    for (int nt = 0; nt < 8; ++nt)
      #pragma unroll
      for (int kt = 0; kt < 8; ++kt) {
        const bf16x8 bfr = *(const bf16x8*)&bs[((nt*8 + kt)*64 + lane)*8];
        acc[0][nt] = __builtin_amdgcn_mfma_f32_16x16x32_bf16(afH[0][kt], bfr, acc[0][nt], 0, 0, 0);
        acc[1][nt] = __builtin_amdgcn_mfma_f32_16x16x32_bf16(afH[1][kt], bfr, acc[1][nt], 0, 0, 0);
        acc[0][nt] = __builtin_amdgcn_mfma_f32_16x16x32_bf16(afL[0][kt], bfr, acc[0][nt], 0, 0, 0);
        acc[1][nt] = __builtin_amdgcn_mfma_f32_16x16x32_bf16(afL[1][kt], bfr, acc[1][nt], 0, 0, 0);
      }

    __syncthreads();
    {
      const uint4* src = (const uint4*)(WAlo + (size_t)chunk * 32768);
      uint4* dst = (uint4*)bs;
      #pragma unroll
      for (int r = 0; r < 16; ++r) dst[r*256 + tid] = src[r*256 + tid];
    }
    __syncthreads();
    #pragma unroll
    for (int nt = 0; nt < 8; ++nt)
      #pragma unroll
      for (int kt = 0; kt < 8; ++kt) {
        const bf16x8 bfr = *(const bf16x8*)&bs[((nt*8 + kt)*64 + lane)*8];
        acc[0][nt] = __builtin_amdgcn_mfma_f32_16x16x32_bf16(afH[0][kt], bfr, acc[0][nt], 0, 0, 0);
        acc[1][nt] = __builtin_amdgcn_mfma_f32_16x16x32_bf16(afH[1][kt], bfr, acc[1][nt], 0, 0, 0);
      }

    // epilogue: two 64-row sub-passes (tile t -> rows row0 + t*64 + 0..63)
    #pragma unroll
    for (int t = 0; t < 2; ++t) {
      __syncthreads();   // B reads (t=0) / prior copy reads (t=1) done
      #pragma unroll
      for (int nt = 0; nt < 8; ++nt) {
        const float bv = ba[chunk*128 + nt*16 + ln];
        float m = 0.f;
        #pragma unroll
        for (int reg = 0; reg < 4; ++reg) {
          float h = acc[t][nt][reg] + bv;
          h = h > 0.f ? h : 0.f;
          bsf[(wave*16 + quad*4 + reg)*140 + nt*16 + ln] = h;
          m = fmaxf(m, h);
        }
        m = fmaxf(m, __shfl_xor(m, 16, 64));
        m = fmaxf(m, __shfl_xor(m, 32, 64));
        if (quad == 0) wsmax[t*4 + wave][nt*16 + ln] = m;
      }
      __syncthreads();
      {
        const int row = tid >> 2, q4 = tid & 3;
        const float* rp = &bsf[row*140 + q4*32];
        bf16* gp = hats + (size_t)(row0 + t*64 + row) * D + chunk*128 + q4*32;
        #pragma unroll
        for (int s = 0; s < 4; ++s) {
          float4 v0 = *(const float4*)&rp[s*8];
          float4 v1 = *(const float4*)&rp[s*8 + 4];
          float vv[8] = {v0.x, v0.y, v0.z, v0.w, v1.x, v1.y, v1.z, v1.w};
          bf16x8 pk;
          #pragma unroll
          for (int e = 0; e < 8; ++e) {
            bf16 b = __float2bfloat16(vv[e]);
            pk[e] = *(short*)&b;
          }
          *(bf16x8*)(gp + s*8) = pk;
        }
      }
    }
    // all 8 wsmax rows written before the last barrier above
    if (tid < 128) {
      float m = wsmax[0][tid];
      #pragma unroll
      for (int w = 1; w < 8; ++w) m = fmaxf(m, wsmax[w][tid]);
      HAts[(size_t)g*D + chunk*128 + tid] = m;
    }
  }
}

// ---------------------------------------------------------------------------
// K-sprep: S = [query | hs | HAts] (512 x 768) -> row-major bf16 hi/lo
// ---------------------------------------------------------------------------
__global__ void k_sprep(const float* __restrict__ query,
                        const float* __restrict__ HAts,
                        const float* __restrict__ xfin,
                        bf16* __restrict__ Shi, bf16* __restrict__ Slo) {
  int m = blockIdx.x * 256 + threadIdx.x;   // 0..767
  int g = blockIdx.y;
  float v;
  if (m < 256)      v = query[(size_t)g*D + m];
  else if (m < 512) v = xfin[(size_t)(m - 256)*LP + 3*g];
  else              v = HAts[(size_t)g*D + (m - 512)];
  bf16 h = __float2bfloat16(v);
  bf16 l = __float2bfloat16(v - __bfloat162float(h));
  Shi[(size_t)g*768 + m] = h;
  Slo[(size_t)g*768 + m] = l;
}

// ---------------------------------------------------------------------------
// K4: Gterm = S @ Wp1[0:768] + bp1 via split-bf16 MFMA.
// ---------------------------------------------------------------------------
__global__ __launch_bounds__(256) void k_gterm_mfma(
    const bf16* __restrict__ Shi, const bf16* __restrict__ Slo,
    const bf16* __restrict__ WB1hi, const bf16* __restrict__ WB1lo,
    const float* __restrict__ bp1, float* __restrict__ Gterm) {
  __shared__ __align__(16) unsigned short bs[32768];  // 64 KB

  const int tid = threadIdx.x;
  const int wave = tid >> 6, lane = tid & 63;
  const int ln = lane & 15, quad = lane >> 4;
  const int nc = blockIdx.x;
  const int row0 = blockIdx.y * 64;

  f32x4 acc[8];
  #pragma unroll
  for (int nt = 0; nt < 8; ++nt) acc[nt] = (f32x4){0.f, 0.f, 0.f, 0.f};

  const uint4* ahp = (const uint4*)(Shi + (size_t)(row0 + wave*16 + ln) * 768);
  const uint4* alp = (const uint4*)(Slo + (size_t)(row0 + wave*16 + ln) * 768);

  for (int kc = 0; kc < 3; ++kc) {
    bf16x8 afH[8], afL[8];
    #pragma unroll
    for (int kt = 0; kt < 8; ++kt) {
      uint4 th = ahp[kc*32 + kt*4 + quad];
      uint4 tl = alp[kc*32 + kt*4 + quad];
      afH[kt] = *(const bf16x8*)&th;
      afL[kt] = *(const bf16x8*)&tl;
    }

    __syncthreads();
    {
      const uint4* src = (const uint4*)(WB1hi + (size_t)(nc*3 + kc) * 32768);
      uint4* dst = (uint4*)bs;
      #pragma unroll
      for (int r = 0; r < 16; ++r) dst[r*256 + tid] = src[r*256 + tid];
    }
    __syncthreads();
    #pragma unroll
    for (int nt = 0; nt < 8; ++nt)
      #pragma unroll
      for (int kt = 0; kt < 8; ++kt) {
        const bf16x8 bfr = *(const bf16x8*)&bs[((nt*8 + kt)*64 + lane)*8];
        acc[nt] = __builtin_amdgcn_mfma_f32_16x16x32_bf16(afH[kt], bfr, acc[nt], 0, 0, 0);
        acc[nt] = __builtin_amdgcn_mfma_f32_16x16x32_bf16(afL[kt], bfr, acc[nt], 0, 0, 0);
      }

    __syncthreads();
    {
      const uint4* src = (const uint4*)(WB1lo + (size_t)(nc*3 + kc) * 32768);
      uint4* dst = (uint4*)bs;
      #pragma unroll
      for (int r = 0; r < 16; ++r) dst[r*256 + tid] = src[r*256 + tid];
    }
    __syncthreads();
    #pragma unroll
    for (int nt = 0; nt < 8; ++nt)
      #pragma unroll
      for (int kt = 0; kt < 8; ++kt) {
        const bf16x8 bfr = *(const bf16x8*)&bs[((nt*8 + kt)*64 + lane)*8];
        acc[nt] = __builtin_amdgcn_mfma_f32_16x16x32_bf16(afH[kt], bfr, acc[nt], 0, 0, 0);
      }
  }

  #pragma unroll
  for (int nt = 0; nt < 8; ++nt) {
    const int col = nc*128 + nt*16 + ln;
    const float bv = bp1[col];
    #pragma unroll
    for (int reg = 0; reg < 4; ++reg)
      Gterm[(size_t)(row0 + wave*16 + quad*4 + reg) * HID + col] = acc[nt][reg] + bv;
  }
}

// ---------------------------------------------------------------------------
// K2: build x0 (C=256, L=1534) transposed sequence
// ---------------------------------------------------------------------------
__global__ void k_build_x0(const float* __restrict__ nodes,
                           const float* __restrict__ HAts,
                           const bf16* __restrict__ hats,
                           const int* __restrict__ act,
                           float* __restrict__ x0) {
  int t = blockIdx.x * 256 + threadIdx.x;
  int c = blockIdx.y;
  if (t >= LSEQ) return;
  float v;
  if (t == LSEQ - 1) {
    v = nodes[(size_t)(G-1)*D + c];
  } else {
    int r = t / 3, m = t - 3*r;
    if (m == 0)      v = nodes[(size_t)r*D + c];
    else if (m == 1) v = HAts[(size_t)r*D + c];
    else             v = __bfloat162float(hats[(size_t)(r*PER + act[r])*D + c]);
  }
  x0[(size_t)c*LP + t] = v;
}

// ---------------------------------------------------------------------------
// K3: TCN conv partials, split-K over cin (blockIdx.z owns CPB chunks of 32).
// ---------------------------------------------------------------------------
template<int DIL, int CPB, bool HASWD>
__global__ __launch_bounds__(256) void k_tcn4(
    const float* __restrict__ xin,
    const float* __restrict__ W,     // (Cout, Cin, 3)
    const float* __restrict__ Wd,    // (Cout, Cin) or unused
    float* __restrict__ ybuf,        // [NZ][Cout][LP]
    float* __restrict__ rbuf,        // [NZ][Cout][LP] (HASWD only)
    int Cin) {
  __shared__ __align__(16) float xs[32][80];
  __shared__ __align__(16) float wst[3][32][68];
  __shared__ __align__(16) float wds[HASWD ? 32 : 1][HASWD ? 68 : 4];

  const int tid = threadIdx.x;
  const int tt = tid & 15;
  const int cc = tid >> 4;
  const int t0 = blockIdx.x * 64;
  const int o0 = blockIdx.y * 64;
  const int Cout = gridDim.y << 6;

  float acc[4][4], res[4][4];
  #pragma unroll
  for (int it = 0; it < 4; ++it)
    #pragma unroll
    for (int ic = 0; ic < 4; ++ic) { acc[it][ic] = 0.f; res[it][ic] = 0.f; }

  for (int c = 0; c < CPB; ++c) {
    const int i0 = (blockIdx.z * CPB + c) * 32;
    __syncthreads();
    for (int idx = tid; idx < 32*20; idx += 256) {
      int r = idx / 20, j4 = idx - r*20;
      int tp = t0 - 16 + j4*4;
      float4 v;
      if (tp >= 0) v = *(const float4*)&xin[(size_t)(i0 + r)*LP + tp];
      else         v = make_float4(0.f, 0.f, 0.f, 0.f);
      *(float4*)&xs[r][j4*4] = v;
    }
    for (int idx = tid; idx < 64*32; idx += 256) {
      int o = idx >> 5, i = idx & 31;
      const float* wp = &W[((size_t)(o0 + o)*Cin + i0 + i)*3];
      wst[0][i][o] = wp[0];
      wst[1][i][o] = wp[1];
      wst[2][i][o] = wp[2];
      if constexpr (HASWD) wds[i][o] = Wd[(size_t)(o0 + o)*Cin + i0 + i];
    }
    __syncthreads();

    const int base = 16 + tt*4;
    #pragma unroll 2
    for (int i = 0; i < 32; ++i) {
      float4 xv0, xv1, xv2;
      if constexpr (DIL == 1) {
        float4 A = *(const float4*)&xs[i][base - 4];
        float4 B = *(const float4*)&xs[i][base];
        xv0 = make_float4(A.z, A.w, B.x, B.y);
        xv1 = make_float4(A.w, B.x, B.y, B.z);
        xv2 = B;
      } else if constexpr (DIL == 2) {
        float4 A = *(const float4*)&xs[i][base - 4];
        float4 B = *(const float4*)&xs[i][base];
        xv0 = A;
        xv1 = make_float4(A.z, A.w, B.x, B.y);
        xv2 = B;
      } else {
        xv0 = *(const float4*)&xs[i][base - 2*DIL];
        xv1 = *(const float4*)&xs[i][base - DIL];
        xv2 = *(const float4*)&xs[i][base];
      }
      float4 w0 = *(const float4*)&wst[0][i][cc*4];
      float4 w1 = *(const float4*)&wst[1][i][cc*4];
      float4 w2 = *(const float4*)&wst[2][i][cc*4];
      #pragma unroll
      for (int it = 0; it < 4; ++it) {
        float x0 = ((const float*)&xv0)[it];
        float x1 = ((const float*)&xv1)[it];
        float x2 = ((const float*)&xv2)[it];
        #pragma unroll
        for (int ic = 0; ic < 4; ++ic) {
          float a = acc[it][ic];
          a = fmaf(x0, ((const float*)&w0)[ic], a);
          a = fmaf(x1, ((const float*)&w1)[ic], a);
          a = fmaf(x2, ((const float*)&w2)[ic], a);
          acc[it][ic] = a;
        }
      }
      if constexpr (HASWD) {
        float4 wd4 = *(const float4*)&wds[i][cc*4];
        #pragma unroll
        for (int it = 0; it < 4; ++it) {
          float x2 = ((const float*)&xv2)[it];
          #pragma unroll
          for (int ic = 0; ic < 4; ++ic)
            res[it][ic] = fmaf(x2, ((const float*)&wd4)[ic], res[it][ic]);
        }
      }
    }
  }

  const int t = t0 + tt*4;
  #pragma unroll
  for (int ic = 0; ic < 4; ++ic) {
    const int ch = o0 + cc*4 + ic;
    const size_t off = ((size_t)blockIdx.z * Cout + ch) * LP + t;
    float4 v = make_float4(acc[0][ic], acc[1][ic], acc[2][ic], acc[3][ic]);
    *(float4*)&ybuf[off] = v;
    if constexpr (HASWD) {
      float4 rv = make_float4(res[0][ic], res[1][ic], res[2][ic], res[3][ic]);
      *(float4*)&rbuf[off] = rv;
    }
  }
}

// ---------------------------------------------------------------------------
// K3b: reduce NZ partial slices: out = relu(relu(sum_y+b) + res)
// ---------------------------------------------------------------------------
template<int NZ, bool HASWD>
__global__ __launch_bounds__(384) void k_tcn_red(
    const float* __restrict__ ybuf, const float* __restrict__ rbuf,
    const float* __restrict__ xin, const float* __restrict__ b,
    float* __restrict__ xout) {
  const int ch = blockIdx.x;
  const int Cout = gridDim.x;
  const int t = threadIdx.x * 4;
  const size_t stride = (size_t)Cout * LP;
  const size_t base = (size_t)ch * LP + t;

  float4 y = *(const float4*)&ybuf[base];
  #pragma unroll
  for (int z = 1; z < NZ; ++z) {
    float4 u = *(const float4*)&ybuf[base + z*stride];
    y.x += u.x; y.y += u.y; y.z += u.z; y.w += u.w;
  }
  const float bv = b[ch];
  y.x = fmaxf(y.x + bv, 0.f); y.y = fmaxf(y.y + bv, 0.f);
  y.z = fmaxf(y.z + bv, 0.f); y.w = fmaxf(y.w + bv, 0.f);

  float4 r;
  if constexpr (HASWD) {
    r = *(const float4*)&rbuf[base];
    #pragma unroll
    for (int z = 1; z < NZ; ++z) {
      float4 u = *(const float4*)&rbuf[base + z*stride];
      r.x += u.x; r.y += u.y; r.z += u.z; r.w += u.w;
    }
  } else {
    r = *(const float4*)&xin[base];
  }
  float4 v;
  v.x = fmaxf(y.x + r.x, 0.f); v.y = fmaxf(y.y + r.y, 0.f);
  v.z = fmaxf(y.z + r.z, 0.f); v.w = fmaxf(y.w + r.w, 0.f);
  *(float4*)&xout[base] = v;
}

// ---------------------------------------------------------------------------
// K5: out[i] = relu(hats[i,:]@Wp1b + Gterm[g,:]) @ Wp2 + bp2.
// 256 threads / 4 waves, 128 rows/block (= one group), 2 row-tiles per wave.
// ---------------------------------------------------------------------------
__global__ __launch_bounds__(256, 2) void k_final_mfma(
    const bf16* __restrict__ hats, const bf16* __restrict__ WBt,
    const float* __restrict__ Gterm, const float* __restrict__ Wp2,
    const float* __restrict__ bp2, float* __restrict__ out) {
  __shared__ __align__(16) unsigned short bs[32768];  // 64 KB
  __shared__ float gs[512];
  __shared__ float w2s[512];

  const int tid = threadIdx.x;
  const int wave = tid >> 6, lane = tid & 63;
  const int ln = lane & 15, quad = lane >> 4;
  const int row0 = blockIdx.x * 128;
  const int g = blockIdx.x;

  gs[tid]        = Gterm[(size_t)g*HID + tid];
  gs[tid + 256]  = Gterm[(size_t)g*HID + tid + 256];
  w2s[tid]       = Wp2[tid];
  w2s[tid + 256] = Wp2[tid + 256];

  bf16x8 afrag[2][8];
  #pragma unroll
  for (int t = 0; t < 2; ++t) {
    const uint4* ap = (const uint4*)(hats + (size_t)(row0 + (t*4 + wave)*16 + ln) * D);
    #pragma unroll
    for (int kt = 0; kt < 8; ++kt) {
      uint4 u = ap[kt*4 + quad];
      afrag[t][kt] = *(const bf16x8*)&u;
    }
  }

  float osum[2][4] = {{0.f,0.f,0.f,0.f},{0.f,0.f,0.f,0.f}};

  for (int chunk = 0; chunk < 4; ++chunk) {
    __syncthreads();
    const uint4* src = (const uint4*)(WBt + (size_t)chunk * 32768);
    uint4* dst = (uint4*)bs;
    #pragma unroll
    for (int r = 0; r < 16; ++r) dst[r*256 + tid] = src[r*256 + tid];
    __syncthreads();

    #pragma unroll
    for (int nt = 0; nt < 8; ++nt) {
      f32x4 acc0 = {0.f, 0.f, 0.f, 0.f};
      f32x4 acc1 = {0.f, 0.f, 0.f, 0.f};
      #pragma unroll
      for (int kt = 0; kt < 8; ++kt) {
        const bf16x8 bfr = *(const bf16x8*)&bs[((nt*8 + kt)*64 + lane)*8];
        acc0 = __builtin_amdgcn_mfma_f32_16x16x32_bf16(afrag[0][kt], bfr, acc0, 0, 0, 0);
        acc1 = __builtin_amdgcn_mfma_f32_16x16x32_bf16(afrag[1][kt], bfr, acc1, 0, 0, 0);
      }
      int n = chunk*128 + nt*16 + ln;
      float gv = gs[n], wv = w2s[n];
      #pragma unroll
      for (int reg = 0; reg < 4; ++reg) {
        float h0 = acc0[reg] + gv;
        h0 = h0 > 0.f ? h0 : 0.f;
        osum[0][reg] = fmaf(h0, wv, osum[0][reg]);
        float h1 = acc1[reg] + gv;
        h1 = h1 > 0.f ? h1 : 0.f;
        osum[1][reg] = fmaf(h1, wv, osum[1][reg]);
      }
    }
  }

  #pragma unroll
  for (int t = 0; t < 2; ++t)
    #pragma unroll
    for (int reg = 0; reg < 4; ++reg) {
      float v = osum[t][reg];
      v += __shfl_xor(v, 1, 64);
      v += __shfl_xor(v, 2, 64);
      v += __shfl_xor(v, 4, 64);
      v += __shfl_xor(v, 8, 64);
      osum[t][reg] = v;
    }
  if (ln == 0) {
    float b2 = bp2[0];
    #pragma unroll
    for (int t = 0; t < 2; ++t)
      #pragma unroll
      for (int reg = 0; reg < 4; ++reg)
        out[row0 + (t*4 + wave)*16 + quad*4 + reg] = osum[t][reg] + b2;
  }
}

// ---------------------------------------------------------------------------
extern "C" void kernel_launch(void* const* d_in, const int* in_sizes, int n_in,
                              void* d_out, int out_size, void* d_ws, size_t ws_size,
                              hipStream_t stream) {
  (void)in_sizes; (void)n_in; (void)out_size; (void)ws_size;
  const float* NEs   = (const float*)d_in[0];
  const float* nodes = (const float*)d_in[1];
  const float* query = (const float*)d_in[2];
  const int*   act   = (const int*)d_in[4];
  const float* Wa    = (const float*)d_in[5];
  const float* ba    = (const float*)d_in[6];
  const float* Wc0   = (const float*)d_in[7];
  const float* bc0   = (const float*)d_in[8];
  const float* Wc1   = (const float*)d_in[9];
  const float* bc1   = (const float*)d_in[10];
  const float* Wd1   = (const float*)d_in[11];
  const float* Wc2   = (const float*)d_in[12];
  const float* bc2   = (const float*)d_in[13];
  const float* Wc3   = (const float*)d_in[14];
  const float* bc3   = (const float*)d_in[15];
  const float* Wd3   = (const float*)d_in[16];
  const float* Wp1   = (const float*)d_in[17];
  const float* bp1   = (const float*)d_in[18];
  const float* Wp2   = (const float*)d_in[19];
  const float* bp2   = (const float*)d_in[20];
  float* out = (float*)d_out;

  char* ws = (char*)d_ws;
  bf16*  hats  = (bf16*)ws;  ws += (size_t)NROW * D * sizeof(bf16);
  float* HAts  = (float*)ws; ws += (size_t)G * D * sizeof(float);
  float* xa    = (float*)ws; ws += (size_t)512 * LP * sizeof(float);
  float* xb    = (float*)ws; ws += (size_t)512 * LP * sizeof(float);
  float* Gterm = (float*)ws; ws += (size_t)G * HID * sizeof(float);
  bf16*  WBt   = (bf16*)ws;  ws += (size_t)D * HID * sizeof(bf16);
  bf16*  WAhi  = (bf16*)ws;  ws += (size_t)D * D * sizeof(bf16);
  bf16*  WAlo  = (bf16*)ws;  ws += (size_t)D * D * sizeof(bf16);
  bf16*  WB1hi = (bf16*)ws;  ws += (size_t)768 * HID * sizeof(bf16);
  bf16*  WB1lo = (bf16*)ws;  ws += (size_t)768 * HID * sizeof(bf16);
  bf16*  Shi   = (bf16*)ws;  ws += (size_t)G * 768 * sizeof(bf16);
  bf16*  Slo   = (bf16*)ws;  ws += (size_t)G * 768 * sizeof(bf16);
  // split-K partial buffers: up to 2048 rows x LP each (12.6 MB each)
  float* P0 = (float*)ws; ws += (size_t)2048 * LP * sizeof(float);
  float* P1 = (float*)ws; ws += (size_t)2048 * LP * sizeof(float);

  k_prep<<<2304, 256, 0, stream>>>(Wa, WAhi, WAlo, Wp1, WBt, WB1hi, WB1lo);
  k_hats_mfma<<<G, 256, 0, stream>>>(NEs, WAhi, WAlo, ba, hats, HAts);
  k_build_x0<<<dim3(6, 256), 256, 0, stream>>>(nodes, HAts, hats, act, xa);

  // L0: 256->256, dil=1, NZ=8 (CPB=1): 768 blocks
  k_tcn4<1, 1, false><<<dim3(24, 4, 8), 256, 0, stream>>>(xa, Wc0, nullptr, P0, nullptr, 256);
  k_tcn_red<8, false><<<256, 384, 0, stream>>>(P0, nullptr, xa, bc0, xb);
  // L1: 256->512, dil=2, Wd, NZ=4 (CPB=2): 768 blocks
  k_tcn4<2, 2, true ><<<dim3(24, 8, 4), 256, 0, stream>>>(xb, Wc1, Wd1, P0, P1, 256);
  k_tcn_red<4, true ><<<512, 384, 0, stream>>>(P0, P1, xb, bc1, xa);
  // L2: 512->512, dil=4, NZ=4 (CPB=4): 768 blocks
  k_tcn4<4, 4, false><<<dim3(24, 8, 4), 256, 0, stream>>>(xa, Wc2, nullptr, P0, nullptr, 512);
  k_tcn_red<4, false><<<512, 384, 0, stream>>>(P0, nullptr, xa, bc2, xb);
  // L3: 512->256, dil=8, Wd, NZ=8 (CPB=2): 768 blocks
  k_tcn4<8, 2, true ><<<dim3(24, 4, 8), 256, 0, stream>>>(xb, Wc3, Wd3, P0, P1, 512);
  k_tcn_red<8, true ><<<256, 384, 0, stream>>>(P0, P1, xb, bc3, xa);

  k_sprep<<<dim3(3, G), 256, 0, stream>>>(query, HAts, xa, Shi, Slo);
  k_gterm_mfma<<<dim3(4, 8), 256, 0, stream>>>(Shi, Slo, WB1hi, WB1lo, bp1, Gterm);
  k_final_mfma<<<G, 256, 0, stream>>>(hats, WBt, Gterm, Wp2, bp2, out);
}

// Round 8
// 353.354 us; speedup vs baseline: 1.0557x; 1.0031x over previous
//
#include <hip/hip_runtime.h>
#include <hip/hip_bf16.h>

#define D 256
#define G 512
#define PER 128
#define NROW (G*PER)   // 65536
#define LSEQ 1534
#define LP 1536
#define HID 512

typedef __hip_bfloat16 bf16;
typedef __attribute__((ext_vector_type(8))) short bf16x8;
typedef __attribute__((ext_vector_type(4))) short bf16x4;
typedef __attribute__((ext_vector_type(4))) float f32x4;

// MFMA fragment layout (conflict-free, lane-indexed): within each 64KB chunk,
// fragment block (nt,kt) occupies 1KB; 16B unit index within block = lane.
// Content: element (k,n): nt=(n>>4)&7, kt=k>>5, unit=((k>>3)&3)*16+(n&15), e=k&7.
// This layout serves BOTH mfma operand slots (A: row=ln,k=quad*8+e;
// B: col=ln,k=quad*8+e). Kernels below use weights as the A-operand
// (swapped) so the D-fragment gives each lane row=ln, n=quad*4+reg.

// ---------------------------------------------------------------------------
// K-prep (fused): waprep (blocks 0..255), wconv (256..767), wp1prep (768..2303)
// ---------------------------------------------------------------------------
__global__ __launch_bounds__(256) void k_prep(
    const float* __restrict__ Wa, bf16* __restrict__ WAhi, bf16* __restrict__ WAlo,
    const float* __restrict__ Wp1, bf16* __restrict__ WBt,
    bf16* __restrict__ WB1hi, bf16* __restrict__ WB1lo) {
  const int b = blockIdx.x, tid = threadIdx.x;
  if (b < 256) {
    int id = b * 256 + tid;          // id = k*256 + n
    int k = id >> 8, n = id & 255;
    float v = Wa[(size_t)k * D + n];
    bf16 h = __float2bfloat16(v);
    bf16 l = __float2bfloat16(v - __bfloat162float(h));
    int dst = (n >> 7) * 32768
            + (((((n >> 4) & 7) * 8 + (k >> 5)) * 64 + ((k >> 3) & 3) * 16 + (n & 15)) * 8)
            + (k & 7);
    WAhi[dst] = h;
    WAlo[dst] = l;
  } else if (b < 768) {
    int id = (b - 256) * 256 + tid;  // id = k*512 + n
    int k = id >> 9, n = id & 511;
    float v = Wp1[(size_t)(768 + k) * HID + n];
    int dst = (n >> 7) * 32768
            + (((((n >> 4) & 7) * 8 + (k >> 5)) * 64 + ((k >> 3) & 3) * 16 + (n & 15)) * 8)
            + (k & 7);
    WBt[dst] = __float2bfloat16(v);
  } else {
    int id = (b - 768) * 256 + tid;  // id = k*512 + n, k<768
    int k = id >> 9, n = id & 511;
    float v = Wp1[(size_t)k * HID + n];
    bf16 h = __float2bfloat16(v);
    bf16 l = __float2bfloat16(v - __bfloat162float(h));
    int kc = k >> 8, kr = k & 255;
    int nc = n >> 7, nr = n & 127;
    int dst = (nc*3 + kc) * 32768
            + ((((nr >> 4) * 8 + (kr >> 5)) * 64 + ((kr >> 3) & 3) * 16 + (nr & 15)) * 8)
            + (kr & 7);
    WB1hi[dst] = h;
    WB1lo[dst] = l;
  }
}

// ---------------------------------------------------------------------------
// K1: hats = relu(NEs @ Wa + ba), swapped-operand split-bf16 MFMA.
// 512 threads / 8 waves, 256 rows/block (= 2 groups), grid 256 (1 block/CU).
// Wave w, tile t owns rows row0 + (w*2+t)*16. D-frag: lane ln = row,
// quad*4+reg = n -> direct bf16x4 stores, no LDS bounce, no barriers in
// epilogue. HAts per group via shfl_xor over ln + LDS combine.
// ---------------------------------------------------------------------------
__global__ __launch_bounds__(512) void k_hats_mfma(
    const float* __restrict__ NEs, const bf16* __restrict__ WAhi,
    const bf16* __restrict__ WAlo, const float* __restrict__ ba,
    bf16* __restrict__ hats, float* __restrict__ HAts) {
  __shared__ __align__(16) unsigned short bs[32768];  // 64 KB stage
  __shared__ float wsmax[8][128];

  const int tid = threadIdx.x;
  const int wave = tid >> 6, lane = tid & 63;
  const int ln = lane & 15, quad = lane >> 4;
  const int row0 = blockIdx.x * 256;

  // NEs fragments (B-operand): 2 tiles/wave, hi/lo split
  bf16x8 afH[2][8], afL[2][8];
  #pragma unroll
  for (int t = 0; t < 2; ++t) {
    const float4* ap = (const float4*)(NEs + (size_t)(row0 + (wave*2 + t)*16 + ln) * D);
    #pragma unroll
    for (int kt = 0; kt < 8; ++kt) {
      float4 x0 = ap[kt*8 + quad*2];
      float4 x1 = ap[kt*8 + quad*2 + 1];
      float xv[8] = {x0.x, x0.y, x0.z, x0.w, x1.x, x1.y, x1.z, x1.w};
      bf16x8 hv, lv;
      #pragma unroll
      for (int e = 0; e < 8; ++e) {
        bf16 h = __float2bfloat16(xv[e]);
        bf16 l = __float2bfloat16(xv[e] - __bfloat162float(h));
        hv[e] = *(short*)&h;
        lv[e] = *(short*)&l;
      }
      afH[t][kt] = hv;
      afL[t][kt] = lv;
    }
  }

  for (int chunk = 0; chunk < 2; ++chunk) {
    f32x4 acc[2][8];
    #pragma unroll
    for (int t = 0; t < 2; ++t)
      #pragma unroll
      for (int nt = 0; nt < 8; ++nt) acc[t][nt] = (f32x4){0.f, 0.f, 0.f, 0.f};

    // stage Wa-hi chunk (weights = A-operand): Wh*xh + Wh*xl
    __syncthreads();
    {
      const uint4* src = (const uint4*)(WAhi + (size_t)chunk * 32768);
      uint4* dst = (uint4*)bs;
      #pragma unroll
      for (int r = 0; r < 8; ++r) dst[r*512 + tid] = src[r*512 + tid];
    }
    __syncthreads();
    #pragma unroll
    for (int nt = 0; nt < 8; ++nt)
      #pragma unroll
      for (int kt = 0; kt < 8; ++kt) {
        const bf16x8 wfr = *(const bf16x8*)&bs[((nt*8 + kt)*64 + lane)*8];
        acc[0][nt] = __builtin_amdgcn_mfma_f32_16x16x32_bf16(wfr, afH[0][kt], acc[0][nt], 0, 0, 0);
        acc[1][nt] = __builtin_amdgcn_mfma_f32_16x16x32_bf16(wfr, afH[1][kt], acc[1][nt], 0, 0, 0);
        acc[0][nt] = __builtin_amdgcn_mfma_f32_16x16x32_bf16(wfr, afL[0][kt], acc[0][nt], 0, 0, 0);
        acc[1][nt] = __builtin_amdgcn_mfma_f32_16x16x32_bf16(wfr, afL[1][kt], acc[1][nt], 0, 0, 0);
      }

    // stage Wa-lo chunk: Wl*xh
    __syncthreads();
    {
      const uint4* src = (const uint4*)(WAlo + (size_t)chunk * 32768);
      uint4* dst = (uint4*)bs;
      #pragma unroll
      for (int r = 0; r < 8; ++r) dst[r*512 + tid] = src[r*512 + tid];
    }
    __syncthreads();
    #pragma unroll
    for (int nt = 0; nt < 8; ++nt)
      #pragma unroll
      for (int kt = 0; kt < 8; ++kt) {
        const bf16x8 wfr = *(const bf16x8*)&bs[((nt*8 + kt)*64 + lane)*8];
        acc[0][nt] = __builtin_amdgcn_mfma_f32_16x16x32_bf16(wfr, afH[0][kt], acc[0][nt], 0, 0, 0);
        acc[1][nt] = __builtin_amdgcn_mfma_f32_16x16x32_bf16(wfr, afH[1][kt], acc[1][nt], 0, 0, 0);
      }

    // epilogue: bias+relu, direct bf16x4 stores, colmax via shfl over ln
    #pragma unroll
    for (int nt = 0; nt < 8; ++nt) {
      const float4 bv = *(const float4*)&ba[chunk*128 + nt*16 + quad*4];
      float m[4];
      #pragma unroll
      for (int t = 0; t < 2; ++t) {
        bf16x4 pk;
        #pragma unroll
        for (int r = 0; r < 4; ++r) {
          float h = acc[t][nt][r] + ((const float*)&bv)[r];
          h = h > 0.f ? h : 0.f;
          bf16 hb = __float2bfloat16(h);
          pk[r] = *(short*)&hb;
          m[r] = (t == 0) ? h : fmaxf(m[r], h);
        }
        bf16* gp = hats + (size_t)(row0 + (wave*2 + t)*16 + ln) * D
                 + chunk*128 + nt*16 + quad*4;
        *(bf16x4*)gp = pk;
      }
      #pragma unroll
      for (int r = 0; r < 4; ++r) {
        m[r] = fmaxf(m[r], __shfl_xor(m[r], 1, 64));
        m[r] = fmaxf(m[r], __shfl_xor(m[r], 2, 64));
        m[r] = fmaxf(m[r], __shfl_xor(m[r], 4, 64));
        m[r] = fmaxf(m[r], __shfl_xor(m[r], 8, 64));
      }
      if (ln == 0) {
        #pragma unroll
        for (int r = 0; r < 4; ++r) wsmax[wave][nt*16 + quad*4 + r] = m[r];
      }
    }
    __syncthreads();
    if (tid < 128) {
      float m = fmaxf(fmaxf(wsmax[0][tid], wsmax[1][tid]),
                      fmaxf(wsmax[2][tid], wsmax[3][tid]));
      HAts[(size_t)(2*blockIdx.x)*D + chunk*128 + tid] = m;
    } else if (tid < 256) {
      int c = tid - 128;
      float m = fmaxf(fmaxf(wsmax[4][c], wsmax[5][c]),
                      fmaxf(wsmax[6][c], wsmax[7][c]));
      HAts[(size_t)(2*blockIdx.x + 1)*D + chunk*128 + c] = m;
    }
  }
}

// ---------------------------------------------------------------------------
// K-sprep: S = [query | hs | HAts] (512 x 768) -> row-major bf16 hi/lo
// ---------------------------------------------------------------------------
__global__ void k_sprep(const float* __restrict__ query,
                        const float* __restrict__ HAts,
                        const float* __restrict__ xfin,
                        bf16* __restrict__ Shi, bf16* __restrict__ Slo) {
  int m = blockIdx.x * 256 + threadIdx.x;   // 0..767
  int g = blockIdx.y;
  float v;
  if (m < 256)      v = query[(size_t)g*D + m];
  else if (m < 512) v = xfin[(size_t)(m - 256)*LP + 3*g];
  else              v = HAts[(size_t)g*D + (m - 512)];
  bf16 h = __float2bfloat16(v);
  bf16 l = __float2bfloat16(v - __bfloat162float(h));
  Shi[(size_t)g*768 + m] = h;
  Slo[(size_t)g*768 + m] = l;
}

// ---------------------------------------------------------------------------
// K4: Gterm = S @ Wp1[0:768] + bp1 via split-bf16 MFMA (original orientation).
// ---------------------------------------------------------------------------
__global__ __launch_bounds__(256) void k_gterm_mfma(
    const bf16* __restrict__ Shi, const bf16* __restrict__ Slo,
    const bf16* __restrict__ WB1hi, const bf16* __restrict__ WB1lo,
    const float* __restrict__ bp1, float* __restrict__ Gterm) {
  __shared__ __align__(16) unsigned short bs[32768];  // 64 KB

  const int tid = threadIdx.x;
  const int wave = tid >> 6, lane = tid & 63;
  const int ln = lane & 15, quad = lane >> 4;
  const int nc = blockIdx.x;
  const int row0 = blockIdx.y * 64;

  f32x4 acc[8];
  #pragma unroll
  for (int nt = 0; nt < 8; ++nt) acc[nt] = (f32x4){0.f, 0.f, 0.f, 0.f};

  const uint4* ahp = (const uint4*)(Shi + (size_t)(row0 + wave*16 + ln) * 768);
  const uint4* alp = (const uint4*)(Slo + (size_t)(row0 + wave*16 + ln) * 768);

  for (int kc = 0; kc < 3; ++kc) {
    bf16x8 afH[8], afL[8];
    #pragma unroll
    for (int kt = 0; kt < 8; ++kt) {
      uint4 th = ahp[kc*32 + kt*4 + quad];
      uint4 tl = alp[kc*32 + kt*4 + quad];
      afH[kt] = *(const bf16x8*)&th;
      afL[kt] = *(const bf16x8*)&tl;
    }

    __syncthreads();
    {
      const uint4* src = (const uint4*)(WB1hi + (size_t)(nc*3 + kc) * 32768);
      uint4* dst = (uint4*)bs;
      #pragma unroll
      for (int r = 0; r < 16; ++r) dst[r*256 + tid] = src[r*256 + tid];
    }
    __syncthreads();
    #pragma unroll
    for (int nt = 0; nt < 8; ++nt)
      #pragma unroll
      for (int kt = 0; kt < 8; ++kt) {
        const bf16x8 bfr = *(const bf16x8*)&bs[((nt*8 + kt)*64 + lane)*8];
        acc[nt] = __builtin_amdgcn_mfma_f32_16x16x32_bf16(afH[kt], bfr, acc[nt], 0, 0, 0);
        acc[nt] = __builtin_amdgcn_mfma_f32_16x16x32_bf16(afL[kt], bfr, acc[nt], 0, 0, 0);
      }

    __syncthreads();
    {
      const uint4* src = (const uint4*)(WB1lo + (size_t)(nc*3 + kc) * 32768);
      uint4* dst = (uint4*)bs;
      #pragma unroll
      for (int r = 0; r < 16; ++r) dst[r*256 + tid] = src[r*256 + tid];
    }
    __syncthreads();
    #pragma unroll
    for (int nt = 0; nt < 8; ++nt)
      #pragma unroll
      for (int kt = 0; kt < 8; ++kt) {
        const bf16x8 bfr = *(const bf16x8*)&bs[((nt*8 + kt)*64 + lane)*8];
        acc[nt] = __builtin_amdgcn_mfma_f32_16x16x32_bf16(afH[kt], bfr, acc[nt], 0, 0, 0);
      }
  }

  #pragma unroll
  for (int nt = 0; nt < 8; ++nt) {
    const int col = nc*128 + nt*16 + ln;
    const float bv = bp1[col];
    #pragma unroll
    for (int reg = 0; reg < 4; ++reg)
      Gterm[(size_t)(row0 + wave*16 + quad*4 + reg) * HID + col] = acc[nt][reg] + bv;
  }
}

// ---------------------------------------------------------------------------
// K2: build x0 (C=256, L=1534) transposed sequence
// ---------------------------------------------------------------------------
__global__ void k_build_x0(const float* __restrict__ nodes,
                           const float* __restrict__ HAts,
                           const bf16* __restrict__ hats,
                           const int* __restrict__ act,
                           float* __restrict__ x0) {
  int t = blockIdx.x * 256 + threadIdx.x;
  int c = blockIdx.y;
  if (t >= LSEQ) return;
  float v;
  if (t == LSEQ - 1) {
    v = nodes[(size_t)(G-1)*D + c];
  } else {
    int r = t / 3, m = t - 3*r;
    if (m == 0)      v = nodes[(size_t)r*D + c];
    else if (m == 1) v = HAts[(size_t)r*D + c];
    else             v = __bfloat162float(hats[(size_t)(r*PER + act[r])*D + c]);
  }
  x0[(size_t)c*LP + t] = v;
}

// ---------------------------------------------------------------------------
// K3: TCN conv partials, split-K over cin (blockIdx.z owns CPB chunks of 32).
// ---------------------------------------------------------------------------
template<int DIL, int CPB, bool HASWD>
__global__ __launch_bounds__(256) void k_tcn4(
    const float* __restrict__ xin,
    const float* __restrict__ W,     // (Cout, Cin, 3)
    const float* __restrict__ Wd,    // (Cout, Cin) or unused
    float* __restrict__ ybuf,        // [NZ][Cout][LP]
    float* __restrict__ rbuf,        // [NZ][Cout][LP] (HASWD only)
    int Cin) {
  __shared__ __align__(16) float xs[32][80];
  __shared__ __align__(16) float wst[3][32][68];
  __shared__ __align__(16) float wds[HASWD ? 32 : 1][HASWD ? 68 : 4];

  const int tid = threadIdx.x;
  const int tt = tid & 15;
  const int cc = tid >> 4;
  const int t0 = blockIdx.x * 64;
  const int o0 = blockIdx.y * 64;
  const int Cout = gridDim.y << 6;

  float acc[4][4], res[4][4];
  #pragma unroll
  for (int it = 0; it < 4; ++it)
    #pragma unroll
    for (int ic = 0; ic < 4; ++ic) { acc[it][ic] = 0.f; res[it][ic] = 0.f; }

  for (int c = 0; c < CPB; ++c) {
    const int i0 = (blockIdx.z * CPB + c) * 32;
    __syncthreads();
    for (int idx = tid; idx < 32*20; idx += 256) {
      int r = idx / 20, j4 = idx - r*20;
      int tp = t0 - 16 + j4*4;
      float4 v;
      if (tp >= 0) v = *(const float4*)&xin[(size_t)(i0 + r)*LP + tp];
      else         v = make_float4(0.f, 0.f, 0.f, 0.f);
      *(float4*)&xs[r][j4*4] = v;
    }
    for (int idx = tid; idx < 64*32; idx += 256) {
      int o = idx >> 5, i = idx & 31;
      const float* wp = &W[((size_t)(o0 + o)*Cin + i0 + i)*3];
      wst[0][i][o] = wp[0];
      wst[1][i][o] = wp[1];
      wst[2][i][o] = wp[2];
      if constexpr (HASWD) wds[i][o] = Wd[(size_t)(o0 + o)*Cin + i0 + i];
    }
    __syncthreads();

    const int base = 16 + tt*4;
    #pragma unroll 2
    for (int i = 0; i < 32; ++i) {
      float4 xv0, xv1, xv2;
      if constexpr (DIL == 1) {
        float4 A = *(const float4*)&xs[i][base - 4];
        float4 B = *(const float4*)&xs[i][base];
        xv0 = make_float4(A.z, A.w, B.x, B.y);
        xv1 = make_float4(A.w, B.x, B.y, B.z);
        xv2 = B;
      } else if constexpr (DIL == 2) {
        float4 A = *(const float4*)&xs[i][base - 4];
        float4 B = *(const float4*)&xs[i][base];
        xv0 = A;
        xv1 = make_float4(A.z, A.w, B.x, B.y);
        xv2 = B;
      } else {
        xv0 = *(const float4*)&xs[i][base - 2*DIL];
        xv1 = *(const float4*)&xs[i][base - DIL];
        xv2 = *(const float4*)&xs[i][base];
      }
      float4 w0 = *(const float4*)&wst[0][i][cc*4];
      float4 w1 = *(const float4*)&wst[1][i][cc*4];
      float4 w2 = *(const float4*)&wst[2][i][cc*4];
      #pragma unroll
      for (int it = 0; it < 4; ++it) {
        float x0 = ((const float*)&xv0)[it];
        float x1 = ((const float*)&xv1)[it];
        float x2 = ((const float*)&xv2)[it];
        #pragma unroll
        for (int ic = 0; ic < 4; ++ic) {
          float a = acc[it][ic];
          a = fmaf(x0, ((const float*)&w0)[ic], a);
          a = fmaf(x1, ((const float*)&w1)[ic], a);
          a = fmaf(x2, ((const float*)&w2)[ic], a);
          acc[it][ic] = a;
        }
      }
      if constexpr (HASWD) {
        float4 wd4 = *(const float4*)&wds[i][cc*4];
        #pragma unroll
        for (int it = 0; it < 4; ++it) {
          float x2 = ((const float*)&xv2)[it];
          #pragma unroll
          for (int ic = 0; ic < 4; ++ic)
            res[it][ic] = fmaf(x2, ((const float*)&wd4)[ic], res[it][ic]);
        }
      }
    }
  }

  const int t = t0 + tt*4;
  #pragma unroll
  for (int ic = 0; ic < 4; ++ic) {
    const int ch = o0 + cc*4 + ic;
    const size_t off = ((size_t)blockIdx.z * Cout + ch) * LP + t;
    float4 v = make_float4(acc[0][ic], acc[1][ic], acc[2][ic], acc[3][ic]);
    *(float4*)&ybuf[off] = v;
    if constexpr (HASWD) {
      float4 rv = make_float4(res[0][ic], res[1][ic], res[2][ic], res[3][ic]);
      *(float4*)&rbuf[off] = rv;
    }
  }
}

// ---------------------------------------------------------------------------
// K3b: reduce NZ partial slices: out = relu(relu(sum_y+b) + res)
// ---------------------------------------------------------------------------
template<int NZ, bool HASWD>
__global__ __launch_bounds__(384) void k_tcn_red(
    const float* __restrict__ ybuf, const float* __restrict__ rbuf,
    const float* __restrict__ xin, const float* __restrict__ b,
    float* __restrict__ xout) {
  const int ch = blockIdx.x;
  const int Cout = gridDim.x;
  const int t = threadIdx.x * 4;
  const size_t stride = (size_t)Cout * LP;
  const size_t base = (size_t)ch * LP + t;

  float4 y = *(const float4*)&ybuf[base];
  #pragma unroll
  for (int z = 1; z < NZ; ++z) {
    float4 u = *(const float4*)&ybuf[base + z*stride];
    y.x += u.x; y.y += u.y; y.z += u.z; y.w += u.w;
  }
  const float bv = b[ch];
  y.x = fmaxf(y.x + bv, 0.f); y.y = fmaxf(y.y + bv, 0.f);
  y.z = fmaxf(y.z + bv, 0.f); y.w = fmaxf(y.w + bv, 0.f);

  float4 r;
  if constexpr (HASWD) {
    r = *(const float4*)&rbuf[base];
    #pragma unroll
    for (int z = 1; z < NZ; ++z) {
      float4 u = *(const float4*)&rbuf[base + z*stride];
      r.x += u.x; r.y += u.y; r.z += u.z; r.w += u.w;
    }
  } else {
    r = *(const float4*)&xin[base];
  }
  float4 v;
  v.x = fmaxf(y.x + r.x, 0.f); v.y = fmaxf(y.y + r.y, 0.f);
  v.z = fmaxf(y.z + r.z, 0.f); v.w = fmaxf(y.w + r.w, 0.f);
  *(float4*)&xout[base] = v;
}

// ---------------------------------------------------------------------------
// K5: out = relu(hats@Wp1b + Gterm)@Wp2 + bp2, swapped-operand MFMA.
// 512 threads / 8 waves, 256 rows/block (2 groups), grid 256.
// Lane holds row=ln, n=quad*4+reg -> per-lane n-accumulation, 2-shuffle
// quad reduction, coalesced f32 stores. No bounce, no osum shuffle tree.
// ---------------------------------------------------------------------------
__global__ __launch_bounds__(512) void k_final_mfma(
    const bf16* __restrict__ hats, const bf16* __restrict__ WBt,
    const float* __restrict__ Gterm, const float* __restrict__ Wp2,
    const float* __restrict__ bp2, float* __restrict__ out) {
  __shared__ __align__(16) unsigned short bs[32768];  // 64 KB
  __shared__ __align__(16) float gs[2][512];
  __shared__ __align__(16) float w2s[512];

  const int tid = threadIdx.x;
  const int wave = tid >> 6, lane = tid & 63;
  const int ln = lane & 15, quad = lane >> 4;
  const int row0 = blockIdx.x * 256;
  const int gw = wave >> 2;   // waves 0-3: group 2b, 4-7: group 2b+1

  gs[0][tid & 511] = Gterm[(size_t)(2*blockIdx.x)*HID + tid];
  gs[1][tid & 511] = Gterm[(size_t)(2*blockIdx.x + 1)*HID + tid];
  if (tid < 512) w2s[tid] = Wp2[tid];

  // hats fragments (B-operand): 2 tiles/wave
  bf16x8 af[2][8];
  #pragma unroll
  for (int t = 0; t < 2; ++t) {
    const uint4* ap = (const uint4*)(hats + (size_t)(row0 + (wave*2 + t)*16 + ln) * D);
    #pragma unroll
    for (int kt = 0; kt < 8; ++kt) {
      uint4 u = ap[kt*4 + quad];
      af[t][kt] = *(const bf16x8*)&u;
    }
  }

  float osum[2] = {0.f, 0.f};

  for (int chunk = 0; chunk < 4; ++chunk) {
    __syncthreads();
    {
      const uint4* src = (const uint4*)(WBt + (size_t)chunk * 32768);
      uint4* dst = (uint4*)bs;
      #pragma unroll
      for (int r = 0; r < 8; ++r) dst[r*512 + tid] = src[r*512 + tid];
    }
    __syncthreads();

    #pragma unroll
    for (int nt = 0; nt < 8; ++nt) {
      f32x4 acc0 = {0.f, 0.f, 0.f, 0.f};
      f32x4 acc1 = {0.f, 0.f, 0.f, 0.f};
      #pragma unroll
      for (int kt = 0; kt < 8; ++kt) {
        const bf16x8 wfr = *(const bf16x8*)&bs[((nt*8 + kt)*64 + lane)*8];
        acc0 = __builtin_amdgcn_mfma_f32_16x16x32_bf16(wfr, af[0][kt], acc0, 0, 0, 0);
        acc1 = __builtin_amdgcn_mfma_f32_16x16x32_bf16(wfr, af[1][kt], acc1, 0, 0, 0);
      }
      const int n4 = chunk*128 + nt*16 + quad*4;
      const float4 gv = *(const float4*)&gs[gw][n4];
      const float4 wv = *(const float4*)&w2s[n4];
      #pragma unroll
      for (int r = 0; r < 4; ++r) {
        float h0 = acc0[r] + ((const float*)&gv)[r];
        h0 = h0 > 0.f ? h0 : 0.f;
        osum[0] = fmaf(h0, ((const float*)&wv)[r], osum[0]);
        float h1 = acc1[r] + ((const float*)&gv)[r];
        h1 = h1 > 0.f ? h1 : 0.f;
        osum[1] = fmaf(h1, ((const float*)&wv)[r], osum[1]);
      }
    }
  }

  // reduce over the 4 quads (lanes ln, ln+16, ln+32, ln+48)
  #pragma unroll
  for (int t = 0; t < 2; ++t) {
    osum[t] += __shfl_xor(osum[t], 16, 64);
    osum[t] += __shfl_xor(osum[t], 32, 64);
  }
  if (quad == 0) {
    float b2 = bp2[0];
    #pragma unroll
    for (int t = 0; t < 2; ++t)
      out[row0 + (wave*2 + t)*16 + ln] = osum[t] + b2;
  }
}

// ---------------------------------------------------------------------------
extern "C" void kernel_launch(void* const* d_in, const int* in_sizes, int n_in,
                              void* d_out, int out_size, void* d_ws, size_t ws_size,
                              hipStream_t stream) {
  (void)in_sizes; (void)n_in; (void)out_size; (void)ws_size;
  const float* NEs   = (const float*)d_in[0];
  const float* nodes = (const float*)d_in[1];
  const float* query = (const float*)d_in[2];
  const int*   act   = (const int*)d_in[4];
  const float* Wa    = (const float*)d_in[5];
  const float* ba    = (const float*)d_in[6];
  const float* Wc0   = (const float*)d_in[7];
  const float* bc0   = (const float*)d_in[8];
  const float* Wc1   = (const float*)d_in[9];
  const float* bc1   = (const float*)d_in[10];
  const float* Wd1   = (const float*)d_in[11];
  const float* Wc2   = (const float*)d_in[12];
  const float* bc2   = (const float*)d_in[13];
  const float* Wc3   = (const float*)d_in[14];
  const float* bc3   = (const float*)d_in[15];
  const float* Wd3   = (const float*)d_in[16];
  const float* Wp1   = (const float*)d_in[17];
  const float* bp1   = (const float*)d_in[18];
  const float* Wp2   = (const float*)d_in[19];
  const float* bp2   = (const float*)d_in[20];
  float* out = (float*)d_out;

  char* ws = (char*)d_ws;
  bf16*  hats  = (bf16*)ws;  ws += (size_t)NROW * D * sizeof(bf16);
  float* HAts  = (float*)ws; ws += (size_t)G * D * sizeof(float);
  float* xa    = (float*)ws; ws += (size_t)512 * LP * sizeof(float);
  float* xb    = (float*)ws; ws += (size_t)512 * LP * sizeof(float);
  float* Gterm = (float*)ws; ws += (size_t)G * HID * sizeof(float);
  bf16*  WBt   = (bf16*)ws;  ws += (size_t)D * HID * sizeof(bf16);
  bf16*  WAhi  = (bf16*)ws;  ws += (size_t)D * D * sizeof(bf16);
  bf16*  WAlo  = (bf16*)ws;  ws += (size_t)D * D * sizeof(bf16);
  bf16*  WB1hi = (bf16*)ws;  ws += (size_t)768 * HID * sizeof(bf16);
  bf16*  WB1lo = (bf16*)ws;  ws += (size_t)768 * HID * sizeof(bf16);
  bf16*  Shi   = (bf16*)ws;  ws += (size_t)G * 768 * sizeof(bf16);
  bf16*  Slo   = (bf16*)ws;  ws += (size_t)G * 768 * sizeof(bf16);
  // split-K partial buffers: up to 2048 rows x LP each (12.6 MB each)
  float* P0 = (float*)ws; ws += (size_t)2048 * LP * sizeof(float);
  float* P1 = (float*)ws; ws += (size_t)2048 * LP * sizeof(float);

  k_prep<<<2304, 256, 0, stream>>>(Wa, WAhi, WAlo, Wp1, WBt, WB1hi, WB1lo);
  k_hats_mfma<<<256, 512, 0, stream>>>(NEs, WAhi, WAlo, ba, hats, HAts);
  k_build_x0<<<dim3(6, 256), 256, 0, stream>>>(nodes, HAts, hats, act, xa);

  // L0: 256->256, dil=1, NZ=8 (CPB=1): 768 blocks
  k_tcn4<1, 1, false><<<dim3(24, 4, 8), 256, 0, stream>>>(xa, Wc0, nullptr, P0, nullptr, 256);
  k_tcn_red<8, false><<<256, 384, 0, stream>>>(P0, nullptr, xa, bc0, xb);
  // L1: 256->512, dil=2, Wd, NZ=4 (CPB=2): 768 blocks
  k_tcn4<2, 2, true ><<<dim3(24, 8, 4), 256, 0, stream>>>(xb, Wc1, Wd1, P0, P1, 256);
  k_tcn_red<4, true ><<<512, 384, 0, stream>>>(P0, P1, xb, bc1, xa);
  // L2: 512->512, dil=4, NZ=4 (CPB=4): 768 blocks
  k_tcn4<4, 4, false><<<dim3(24, 8, 4), 256, 0, stream>>>(xa, Wc2, nullptr, P0, nullptr, 512);
  k_tcn_red<4, false><<<512, 384, 0, stream>>>(P0, nullptr, xa, bc2, xb);
  // L3: 512->256, dil=8, Wd, NZ=8 (CPB=2): 768 blocks
  k_tcn4<8, 2, true ><<<dim3(24, 4, 8), 256, 0, stream>>>(xb, Wc3, Wd3, P0, P1, 512);
  k_tcn_red<8, true ><<<256, 384, 0, stream>>>(P0, P1, xb, bc3, xa);

  k_sprep<<<dim3(3, G), 256, 0, stream>>>(query, HAts, xa, Shi, Slo);
  k_gterm_mfma<<<dim3(4, 8), 256, 0, stream>>>(Shi, Slo, WB1hi, WB1lo, bp1, Gterm);
  k_final_mfma<<<256, 512, 0, stream>>>(hats, WBt, Gterm, Wp2, bp2, out);
}